// Round 1
// baseline (467.152 us; speedup 1.0000x reference)
//
#include <hip/hip_runtime.h>
#include <hip/hip_bf16.h>

// Fused 1x1conv-QKV + per-(b,hw) attention + 1x1conv-out + residual.
// One workgroup per (b,hw): 2048 blocks x 256 threads (4 waves).
// All GEMMs via mfma_f32_16x16x32_bf16, fp32 accumulate.

typedef __bf16 bf16_t;
typedef bf16_t bf16x8 __attribute__((ext_vector_type(8)));
typedef bf16_t bf16x4 __attribute__((ext_vector_type(4)));
typedef float  f32x4  __attribute__((ext_vector_type(4)));

#define NB   8
#define NC   256
#define ND   64
#define NHW  256
#define NS   128

struct SMem {
  union {
    bf16_t xT[ND * NC];            // 32 KB  [d][c]   (QKV phase)
    struct {
      bf16_t aT[ND * ND];          // 8 KB   [j][i]   (attn phase)
      bf16_t attT[ND * NS];        // 16 KB  [j][s]
    } p2;
  } u;
  bf16_t kT[ND * NS];              // 16 KB  [i=d][s]
  bf16_t qT[ND * NS];              // 16 KB  [j=d][s]
  bf16_t vS[NS * ND];              // 16 KB  [s][i=d]
};                                  // total 80 KB -> 2 blocks/CU

// XOR swizzle on element index within a row: spreads rows across bank phases.
// Preserves 8-aligned runs (reads) and 4-aligned runs within 8-blocks (writes).
__device__ __forceinline__ int swz(int row, int col) {
  return col ^ ((row & 7) << 3);
}

__device__ __forceinline__ bf16x8 pack8(float4 a, float4 b) {
  bf16x8 r;
  r[0] = (bf16_t)a.x; r[1] = (bf16_t)a.y; r[2] = (bf16_t)a.z; r[3] = (bf16_t)a.w;
  r[4] = (bf16_t)b.x; r[5] = (bf16_t)b.y; r[6] = (bf16_t)b.z; r[7] = (bf16_t)b.w;
  return r;
}

// 8 contiguous fp32 from global (L2-hot weights) -> bf16x8 fragment
__device__ __forceinline__ bf16x8 ldg_w8(const float* p) {
  float4 a = *(const float4*)p;
  float4 b = *(const float4*)(p + 4);
  return pack8(a, b);
}

__global__ __launch_bounds__(256) void attn_fused(
    const float* __restrict__ x,
    const float* __restrict__ wk, const float* __restrict__ bk,
    const float* __restrict__ wq, const float* __restrict__ bq,
    const float* __restrict__ wv, const float* __restrict__ bv,
    const float* __restrict__ wo, const float* __restrict__ bo,
    float* __restrict__ out) {
  __shared__ SMem sm;
  const int gid  = blockIdx.x;
  const int b    = gid & 7;        // batch -> XCD (b = gid % 8 = XCD id)
  const int hw   = gid >> 3;
  const int t    = threadIdx.x;
  const int w    = t >> 6;         // wave 0..3
  const int lane = t & 63;
  const int l16  = lane & 15;
  const int q4   = lane >> 4;

  const float* xb = x + (size_t)b * NC * ND * NHW + hw;

  // ---- stage 0: gather X[c][d] (stride-256 fp32) -> LDS xT[d][c] bf16 ----
  {
    const int d  = t & 63;
    const int cb = (t >> 6) * 64;
    for (int jj = 0; jj < 8; ++jj) {
      bf16x8 pk;
      #pragma unroll
      for (int e = 0; e < 8; ++e) {
        int c = cb + jj * 8 + e;
        pk[e] = (bf16_t)xb[(size_t)(c * ND + d) * NHW];
      }
      *(bf16x8*)&sm.u.xT[d * NC + swz(d, cb + jj * 8)] = pk;
    }
  }
  __syncthreads();

  // ---- stage 1: K^T[d][s], Q^T[d][s] = X^T * W^T  (waves 0,1: K; 2,3: Q) ----
  {
    const int mat = w >> 1;
    const int sb  = (w & 1) * 64;
    const float* wm = mat ? wq : wk;
    const float* bm = mat ? bq : bk;
    bf16_t* dst = mat ? sm.qT : sm.kT;
    f32x4 acc[4][4] = {};
    for (int ks = 0; ks < 8; ++ks) {
      const int kb = ks * 32 + q4 * 8;
      bf16x8 afr[4];
      #pragma unroll
      for (int mt = 0; mt < 4; ++mt) {
        int row = mt * 16 + l16;
        afr[mt] = *(const bf16x8*)&sm.u.xT[row * NC + swz(row, kb)];
      }
      #pragma unroll
      for (int st = 0; st < 4; ++st) {
        int s = sb + st * 16 + l16;
        bf16x8 bfr = ldg_w8(wm + s * NC + kb);   // B[k=c][n=s] = W[s][c]
        #pragma unroll
        for (int mt = 0; mt < 4; ++mt)
          acc[mt][st] = __builtin_amdgcn_mfma_f32_16x16x32_bf16(afr[mt], bfr, acc[mt][st], 0, 0, 0);
      }
    }
    #pragma unroll
    for (int st = 0; st < 4; ++st) {
      int s = sb + st * 16 + l16;
      float bias = bm[s];
      #pragma unroll
      for (int mt = 0; mt < 4; ++mt) {
        #pragma unroll
        for (int r = 0; r < 4; ++r) {
          int d = mt * 16 + q4 * 4 + r;         // C: row = 4*q4+r, col = l16
          dst[d * NS + swz(d, s)] = (bf16_t)(acc[mt][st][r] + bias);
        }
      }
    }
  }

  // ---- stage 2: V[s][d] = Wv * X  (each wave: 32 s-rows) ----
  {
    const int sb = w * 32;
    f32x4 acc[2][4] = {};
    for (int ks = 0; ks < 8; ++ks) {
      const int kb = ks * 32 + q4 * 8;
      bf16x8 afr[2];
      #pragma unroll
      for (int mt = 0; mt < 2; ++mt)
        afr[mt] = ldg_w8(wv + (sb + mt * 16 + l16) * NC + kb);  // A[m=s][k=c]
      #pragma unroll
      for (int nt = 0; nt < 4; ++nt) {
        int row = nt * 16 + l16;
        bf16x8 bfr = *(const bf16x8*)&sm.u.xT[row * NC + swz(row, kb)]; // B[k=c][n=d]=xT[d][c]
        #pragma unroll
        for (int mt = 0; mt < 2; ++mt)
          acc[mt][nt] = __builtin_amdgcn_mfma_f32_16x16x32_bf16(afr[mt], bfr, acc[mt][nt], 0, 0, 0);
      }
    }
    #pragma unroll
    for (int mt = 0; mt < 2; ++mt) {
      #pragma unroll
      for (int r = 0; r < 4; ++r) {
        int s = sb + mt * 16 + q4 * 4 + r;
        float bias = bv[s];
        #pragma unroll
        for (int nt = 0; nt < 4; ++nt) {
          int d = nt * 16 + l16;
          sm.vS[s * ND + swz(s, d)] = (bf16_t)(acc[mt][nt][r] + bias);
        }
      }
    }
  }
  __syncthreads();

  // ---- stage 3: scores[i][j] = sum_s kT[i][s]*qT[j][s]; softmax over i -> aT[j][i] ----
  {
    f32x4 sacc[4] = {};
    for (int ks = 0; ks < 4; ++ks) {
      const int kb = ks * 32 + q4 * 8;
      int jrow = w * 16 + l16;
      bf16x8 bfr = *(const bf16x8*)&sm.qT[jrow * NS + swz(jrow, kb)]; // B[k=s][n=j]
      #pragma unroll
      for (int it = 0; it < 4; ++it) {
        int irow = it * 16 + l16;
        bf16x8 afr = *(const bf16x8*)&sm.kT[irow * NS + swz(irow, kb)]; // A[m=i][k=s]
        sacc[it] = __builtin_amdgcn_mfma_f32_16x16x32_bf16(afr, bfr, sacc[it], 0, 0, 0);
      }
    }
    const float scale = 0.088388347648318447f;  // 1/sqrt(128)
    float ps[16];
    float mx = -1e30f;
    #pragma unroll
    for (int it = 0; it < 4; ++it) {
      #pragma unroll
      for (int r = 0; r < 4; ++r) {
        float vv = sacc[it][r] * scale;
        ps[it * 4 + r] = vv;
        mx = fmaxf(mx, vv);
      }
    }
    mx = fmaxf(mx, __shfl_xor(mx, 16));   // reduce over quarters (same j)
    mx = fmaxf(mx, __shfl_xor(mx, 32));
    float sum = 0.f;
    #pragma unroll
    for (int i = 0; i < 16; ++i) { ps[i] = __expf(ps[i] - mx); sum += ps[i]; }
    sum += __shfl_xor(sum, 16);
    sum += __shfl_xor(sum, 32);
    float inv = 1.f / sum;
    int j = w * 16 + l16;
    #pragma unroll
    for (int it = 0; it < 4; ++it) {
      bf16x4 pk;
      #pragma unroll
      for (int r = 0; r < 4; ++r) pk[r] = (bf16_t)(ps[it * 4 + r] * inv);
      *(bf16x4*)&sm.u.p2.aT[j * ND + swz(j, it * 16 + q4 * 4)] = pk; // aT[j][i]
    }
  }
  __syncthreads();

  // ---- stage 4: att[s][j] = sum_i V[s][i]*a[i][j] -> attT[j][s] ----
  {
    const int sb = w * 32;
    f32x4 acc[2][4] = {};
    #pragma unroll
    for (int ki = 0; ki < 2; ++ki) {
      const int kb = ki * 32 + q4 * 8;
      bf16x8 afr[2];
      #pragma unroll
      for (int mt = 0; mt < 2; ++mt) {
        int srow = sb + mt * 16 + l16;
        afr[mt] = *(const bf16x8*)&sm.vS[srow * ND + swz(srow, kb)];  // A[m=s][k=i]
      }
      #pragma unroll
      for (int nt = 0; nt < 4; ++nt) {
        int jrow = nt * 16 + l16;
        bf16x8 bfr = *(const bf16x8*)&sm.u.p2.aT[jrow * ND + swz(jrow, kb)]; // B[k=i][n=j]
        #pragma unroll
        for (int mt = 0; mt < 2; ++mt)
          acc[mt][nt] = __builtin_amdgcn_mfma_f32_16x16x32_bf16(afr[mt], bfr, acc[mt][nt], 0, 0, 0);
      }
    }
    #pragma unroll
    for (int nt = 0; nt < 4; ++nt) {
      int j = nt * 16 + l16;
      #pragma unroll
      for (int mt = 0; mt < 2; ++mt) {
        bf16x4 pk;
        #pragma unroll
        for (int r = 0; r < 4; ++r) pk[r] = (bf16_t)acc[mt][nt][r];
        *(bf16x4*)&sm.u.p2.attT[j * NS + swz(j, sb + mt * 16 + q4 * 4)] = pk;
      }
    }
  }
  __syncthreads();

  // ---- stage 5: out[c][d] = sum_s wo[c][s]*att[s][d] + bo[c] + x ----
  {
    const int cb = w * 64;
    f32x4 acc[4][4] = {};
    for (int ks = 0; ks < 4; ++ks) {
      const int kb = ks * 32 + q4 * 8;
      bf16x8 afr[4];
      #pragma unroll
      for (int mt = 0; mt < 4; ++mt)
        afr[mt] = ldg_w8(wo + (cb + mt * 16 + l16) * NS + kb);  // A[m=c][k=s]
      #pragma unroll
      for (int nt = 0; nt < 4; ++nt) {
        int jrow = nt * 16 + l16;
        bf16x8 bfr = *(const bf16x8*)&sm.u.p2.attT[jrow * NS + swz(jrow, kb)]; // B[k=s][n=d]
        #pragma unroll
        for (int mt = 0; mt < 4; ++mt)
          acc[mt][nt] = __builtin_amdgcn_mfma_f32_16x16x32_bf16(afr[mt], bfr, acc[mt][nt], 0, 0, 0);
      }
    }
    #pragma unroll
    for (int mt = 0; mt < 4; ++mt) {
      #pragma unroll
      for (int r = 0; r < 4; ++r) {
        int c = cb + mt * 16 + q4 * 4 + r;
        float bias = bo[c];
        #pragma unroll
        for (int nt = 0; nt < 4; ++nt) {
          int d = nt * 16 + l16;
          size_t gi = (size_t)(((b * NC + c) * ND + d) * NHW + hw);
          out[gi] = acc[mt][nt][r] + bias + x[gi];
        }
      }
    }
  }
}

extern "C" void kernel_launch(void* const* d_in, const int* in_sizes, int n_in,
                              void* d_out, int out_size, void* d_ws, size_t ws_size,
                              hipStream_t stream) {
  const float* x  = (const float*)d_in[0];
  const float* wk = (const float*)d_in[1];
  const float* bk = (const float*)d_in[2];
  const float* wq = (const float*)d_in[3];
  const float* bq = (const float*)d_in[4];
  const float* wv = (const float*)d_in[5];
  const float* bv = (const float*)d_in[6];
  const float* wo = (const float*)d_in[7];
  const float* bo = (const float*)d_in[8];
  float* out = (float*)d_out;
  attn_fused<<<dim3(2048), dim3(256), 0, stream>>>(x, wk, bk, wq, bq, wv, bv, wo, bo, out);
}

// Round 2
// 244.402 us; speedup vs baseline: 1.9114x; 1.9114x over previous
//
#include <hip/hip_runtime.h>
#include <hip/hip_bf16.h>

// 4-kernel coalesced pipeline:
//   T: x [b][c][d][hw] fp32 -> xT [b][d][hw][c] bf16
//   A: QKV projection GEMM (from xT), k/q -> [b][hw][d][s], v -> [b][hw][s][d]
//   B: per-(b,hw) attention (round-1 verified core), att -> [b][d][hw][s]
//   C: out-projection + bias + residual -> out [b][c][d][hw]
// Fallback: round-1 fused kernel if workspace too small.

typedef __bf16 bf16_t;
typedef bf16_t bf16x8 __attribute__((ext_vector_type(8)));
typedef bf16_t bf16x4 __attribute__((ext_vector_type(4)));
typedef float  f32x4  __attribute__((ext_vector_type(4)));

#define NB   8
#define NC   256
#define ND   64
#define NHW  256
#define NS   128

__device__ __forceinline__ int swz(int row, int col) {
  return col ^ ((row & 7) << 3);
}

__device__ __forceinline__ bf16x8 pack8(float4 a, float4 b) {
  bf16x8 r;
  r[0] = (bf16_t)a.x; r[1] = (bf16_t)a.y; r[2] = (bf16_t)a.z; r[3] = (bf16_t)a.w;
  r[4] = (bf16_t)b.x; r[5] = (bf16_t)b.y; r[6] = (bf16_t)b.z; r[7] = (bf16_t)b.w;
  return r;
}

__device__ __forceinline__ bf16x8 ldg_w8(const float* p) {
  float4 a = *(const float4*)p;
  float4 b = *(const float4*)(p + 4);
  return pack8(a, b);
}

// ================= Kernel T: transpose x -> xT bf16 =================
// grid 8192 = 4(ct) * 4(hwt) * 64(d) * 8(b); tile 64c x 64hw for one (b,d)
__global__ __launch_bounds__(256) void transpose_x(
    const float* __restrict__ x, bf16_t* __restrict__ xT) {
  __shared__ bf16_t tile[64 * 72];   // [hw][c] pad to 72 (144B rows)
  const int bid = blockIdx.x;
  const int ct = bid & 3, hwt = (bid >> 2) & 3;
  const int d = (bid >> 4) & 63, b = bid >> 10;
  const int c0 = ct * 64, hw0 = hwt * 64;
  const int t = threadIdx.x;
  const int hwq = t & 15, chi = t >> 4;

  #pragma unroll
  for (int q = 0; q < 4; ++q) {
    int c = q * 16 + chi;
    float4 v4 = *(const float4*)(x + ((size_t)((b * NC + c0 + c) * ND + d)) * NHW + hw0 + hwq * 4);
    tile[(hwq * 4 + 0) * 72 + c] = (bf16_t)v4.x;
    tile[(hwq * 4 + 1) * 72 + c] = (bf16_t)v4.y;
    tile[(hwq * 4 + 2) * 72 + c] = (bf16_t)v4.z;
    tile[(hwq * 4 + 3) * 72 + c] = (bf16_t)v4.w;
  }
  __syncthreads();
  #pragma unroll
  for (int i = 0; i < 2; ++i) {
    int idx = t + 256 * i;
    int hw = idx >> 3, q = idx & 7;
    bf16x8 v8 = *(const bf16x8*)&tile[hw * 72 + q * 8];
    *(bf16x8*)(xT + ((size_t)((b * ND + d) * NHW + hw0 + hw)) * NC + c0 + q * 8) = v8;
  }
}

// ================= Kernel A: QKV projection =================
// grid 1536 = 3(p, fastest) * 8(b) * 64(ht of 4 hw)
// out tile [128 s][n=256 = 64d x 4hw]; 4 waves: mh=w>>1 (s-half), nh=w&1 (n-half)
__global__ __launch_bounds__(256, 2) void qkv_proj(
    const bf16_t* __restrict__ xT,
    const float* __restrict__ wk, const float* __restrict__ bk,
    const float* __restrict__ wq, const float* __restrict__ bq,
    const float* __restrict__ wv, const float* __restrict__ bv,
    bf16_t* __restrict__ kT_ws, bf16_t* __restrict__ qT_ws,
    bf16_t* __restrict__ v_ws) {
  __shared__ union {
    bf16_t slab[256 * 72];       // [n][c64 + pad] 36 KB
    bf16_t dump[4 * 64 * 128];   // 64 KB epilogue staging
  } sm;
  const int bid = blockIdx.x;
  const int p = bid % 3;
  const int rb = bid / 3;
  const int b = rb & 7;
  const int ht = rb >> 3;
  const int t = threadIdx.x, w = t >> 6, lane = t & 63;
  const int l16 = lane & 15, g = lane >> 4;
  const int mh = w >> 1, nh = w & 1;
  const float* wm = (p == 0) ? wk : (p == 1) ? wq : wv;
  const float* bm = (p == 0) ? bk : (p == 1) ? bq : bv;

  const int prt = t & 7, hws = (t >> 3) & 3, dlo = t >> 5;

  f32x4 acc[4][8] = {};
  for (int ck = 0; ck < 4; ++ck) {
    const int c0 = ck * 64;
    if (ck) __syncthreads();
    #pragma unroll
    for (int i = 0; i < 8; ++i) {
      int d = i * 8 + dlo;
      int n = d * 4 + hws;
      bf16x8 v8 = *(const bf16x8*)(xT + ((size_t)((b * ND + d) * NHW + ht * 4 + hws)) * NC + c0 + prt * 8);
      *(bf16x8*)&sm.slab[n * 72 + prt * 8] = v8;
    }
    __syncthreads();
    #pragma unroll
    for (int kf = 0; kf < 2; ++kf) {
      bf16x8 af[4];
      #pragma unroll
      for (int mt = 0; mt < 4; ++mt) {
        int s = mh * 64 + mt * 16 + l16;
        af[mt] = ldg_w8(wm + (size_t)s * NC + c0 + kf * 32 + g * 8);
      }
      #pragma unroll
      for (int nf = 0; nf < 8; ++nf) {
        int n = (nh * 8 + nf) * 16 + l16;
        bf16x8 bfr = *(const bf16x8*)&sm.slab[n * 72 + kf * 32 + g * 8];
        #pragma unroll
        for (int mt = 0; mt < 4; ++mt)
          acc[mt][nf] = __builtin_amdgcn_mfma_f32_16x16x32_bf16(af[mt], bfr, acc[mt][nf], 0, 0, 0);
      }
    }
  }
  __syncthreads();

  if (p < 2) {
    // k/q: stage [hwl][d][s] (8B-slot XOR) then dump [b][hw][d][s]
    #pragma unroll
    for (int mt = 0; mt < 4; ++mt) {
      int s0 = mh * 64 + mt * 16 + g * 4;
      float b0 = bm[s0], b1 = bm[s0 + 1], b2 = bm[s0 + 2], b3 = bm[s0 + 3];
      #pragma unroll
      for (int nf = 0; nf < 8; ++nf) {
        int n = (nh * 8 + nf) * 16 + l16;
        int d = n >> 2, hwl = n & 3;
        int slot = (s0 >> 2) ^ ((d & 7) << 1) ^ (hwl << 3);
        bf16x4 pk;
        pk[0] = (bf16_t)(acc[mt][nf][0] + b0);
        pk[1] = (bf16_t)(acc[mt][nf][1] + b1);
        pk[2] = (bf16_t)(acc[mt][nf][2] + b2);
        pk[3] = (bf16_t)(acc[mt][nf][3] + b3);
        *(bf16x4*)&sm.dump[hwl * 8192 + d * 128 + slot * 4] = pk;
      }
    }
    __syncthreads();
    bf16_t* dst0 = ((p == 0) ? kT_ws : qT_ws) +
                   ((size_t)((b * NHW + ht * 4 + w) * ND + lane)) * NS;
    const int dd = lane, hh = w;
    #pragma unroll
    for (int j = 0; j < 16; ++j) {
      int slotp = (2 * j) ^ ((dd & 7) << 1) ^ (hh << 3);
      bf16x8 v8 = *(const bf16x8*)&sm.dump[hh * 8192 + dd * 128 + slotp * 4];
      *(bf16x8*)(dst0 + j * 8) = v8;
    }
  } else {
    // v: stage [hwl][s][d] (16B d-group XOR by s) then dump [b][hw][s][d]
    #pragma unroll
    for (int mt = 0; mt < 4; ++mt) {
      int s0 = mh * 64 + mt * 16 + g * 4;
      float bb0 = bm[s0], bb1 = bm[s0 + 1], bb2 = bm[s0 + 2], bb3 = bm[s0 + 3];
      #pragma unroll
      for (int nf = 0; nf < 8; ++nf) {
        int n = (nh * 8 + nf) * 16 + l16;
        int d = n >> 2, hwl = n & 3;
        float av[4] = {acc[mt][nf][0] + bb0, acc[mt][nf][1] + bb1,
                       acc[mt][nf][2] + bb2, acc[mt][nf][3] + bb3};
        #pragma unroll
        for (int r = 0; r < 4; ++r) {
          int s = s0 + r;
          sm.dump[hwl * 8192 + s * 64 + (((d >> 3) ^ (s & 7)) << 3) + (d & 7)] = (bf16_t)av[r];
        }
      }
    }
    __syncthreads();
    #pragma unroll
    for (int i = 0; i < 2; ++i) {
      int row = t + 256 * i;
      int hh = row >> 7, s = row & 127;
      bf16_t* dst = v_ws + ((size_t)((b * NHW + ht * 4 + hh) * NS + s)) * ND;
      #pragma unroll
      for (int j = 0; j < 8; ++j) {
        bf16x8 v8 = *(const bf16x8*)&sm.dump[hh * 8192 + s * 64 + ((j ^ (s & 7)) << 3)];
        *(bf16x8*)(dst + j * 8) = v8;
      }
    }
  }
}

// ================= Kernel B: attention core =================
// grid 2048: one block per (b,hw); round-1 verified math, linear global I/O
__global__ __launch_bounds__(256, 2) void attn_core(
    const bf16_t* __restrict__ kT_ws, const bf16_t* __restrict__ qT_ws,
    const bf16_t* __restrict__ v_ws, bf16_t* __restrict__ att_ws) {
  __shared__ struct {
    bf16_t kT[ND * NS];    // [i=d][s] swz
    bf16_t qT[ND * NS];    // [j=d][s] swz
    bf16_t vS[NS * ND];    // [s][i=d] swz
    bf16_t aT[ND * ND];    // [j][i]   swz
    bf16_t attT[ND * NS];  // [j=d][s] swz
  } sm;
  const int gid = blockIdx.x;
  const int b = gid >> 8, hw = gid & 255;
  const int t = threadIdx.x, w = t >> 6, lane = t & 63;
  const int l16 = lane & 15, q4 = lane >> 4;
  const size_t base = (size_t)(b * NHW + hw) * 8192;

  // stage in: linear 16 KB copies with row-swizzled LDS dests
  #pragma unroll
  for (int j = 0; j < 4; ++j) {
    int f = j * 2048 + t * 8;
    int d = f >> 7, s0 = f & 127;
    *(bf16x8*)&sm.kT[d * NS + (s0 ^ ((d & 7) << 3))] = *(const bf16x8*)(kT_ws + base + f);
    *(bf16x8*)&sm.qT[d * NS + (s0 ^ ((d & 7) << 3))] = *(const bf16x8*)(qT_ws + base + f);
    int ss = f >> 6, d0 = f & 63;
    *(bf16x8*)&sm.vS[ss * ND + (d0 ^ ((ss & 7) << 3))] = *(const bf16x8*)(v_ws + base + f);
  }
  __syncthreads();

  // scores[i][j] = sum_s kT[i][s]*qT[j][s]; softmax over i -> aT[j][i]
  {
    f32x4 sacc[4] = {};
    for (int ks = 0; ks < 4; ++ks) {
      const int kb = ks * 32 + q4 * 8;
      int jrow = w * 16 + l16;
      bf16x8 bfr = *(const bf16x8*)&sm.qT[jrow * NS + swz(jrow, kb)];
      #pragma unroll
      for (int it = 0; it < 4; ++it) {
        int irow = it * 16 + l16;
        bf16x8 afr = *(const bf16x8*)&sm.kT[irow * NS + swz(irow, kb)];
        sacc[it] = __builtin_amdgcn_mfma_f32_16x16x32_bf16(afr, bfr, sacc[it], 0, 0, 0);
      }
    }
    const float scale = 0.088388347648318447f;  // 1/sqrt(128)
    float ps[16];
    float mx = -1e30f;
    #pragma unroll
    for (int it = 0; it < 4; ++it) {
      #pragma unroll
      for (int r = 0; r < 4; ++r) {
        float vv = sacc[it][r] * scale;
        ps[it * 4 + r] = vv;
        mx = fmaxf(mx, vv);
      }
    }
    mx = fmaxf(mx, __shfl_xor(mx, 16));
    mx = fmaxf(mx, __shfl_xor(mx, 32));
    float sum = 0.f;
    #pragma unroll
    for (int i = 0; i < 16; ++i) { ps[i] = __expf(ps[i] - mx); sum += ps[i]; }
    sum += __shfl_xor(sum, 16);
    sum += __shfl_xor(sum, 32);
    float inv = 1.f / sum;
    int j = w * 16 + l16;
    #pragma unroll
    for (int it = 0; it < 4; ++it) {
      bf16x4 pk;
      #pragma unroll
      for (int r = 0; r < 4; ++r) pk[r] = (bf16_t)(ps[it * 4 + r] * inv);
      *(bf16x4*)&sm.aT[j * ND + swz(j, it * 16 + q4 * 4)] = pk;
    }
  }
  __syncthreads();

  // att[s][j] = sum_i v[s][i]*a[i][j] -> attT[j][s]
  {
    const int sb = w * 32;
    f32x4 acc[2][4] = {};
    #pragma unroll
    for (int ki = 0; ki < 2; ++ki) {
      const int kb = ki * 32 + q4 * 8;
      bf16x8 afr[2];
      #pragma unroll
      for (int mt = 0; mt < 2; ++mt) {
        int srow = sb + mt * 16 + l16;
        afr[mt] = *(const bf16x8*)&sm.vS[srow * ND + swz(srow, kb)];
      }
      #pragma unroll
      for (int nt = 0; nt < 4; ++nt) {
        int jrow = nt * 16 + l16;
        bf16x8 bfr = *(const bf16x8*)&sm.aT[jrow * ND + swz(jrow, kb)];
        #pragma unroll
        for (int mt = 0; mt < 2; ++mt)
          acc[mt][nt] = __builtin_amdgcn_mfma_f32_16x16x32_bf16(afr[mt], bfr, acc[mt][nt], 0, 0, 0);
      }
    }
    #pragma unroll
    for (int nt = 0; nt < 4; ++nt) {
      int j = nt * 16 + l16;
      #pragma unroll
      for (int mt = 0; mt < 2; ++mt) {
        bf16x4 pk;
        #pragma unroll
        for (int r = 0; r < 4; ++r) pk[r] = (bf16_t)acc[mt][nt][r];
        *(bf16x4*)&sm.attT[j * NS + swz(j, sb + mt * 16 + q4 * 4)] = pk;
      }
    }
  }
  __syncthreads();

  // dump attT -> att_ws[b][d][hw][s]
  #pragma unroll
  for (int j = 0; j < 4; ++j) {
    int f = j * 2048 + t * 8;
    int d = f >> 7, s0 = f & 127;
    bf16x8 v8 = *(const bf16x8*)&sm.attT[d * NS + (s0 ^ ((d & 7) << 3))];
    *(bf16x8*)(att_ws + ((size_t)((b * ND + d) * NHW + hw)) * NS + s0) = v8;
  }
}

// ================= Kernel C: out projection + residual =================
// grid 1024 = 8(ht of 32hw) * 8(dc of 8d) * 2(ch of 128c) * 8(b)
__global__ __launch_bounds__(256, 2) void out_proj(
    const bf16_t* __restrict__ att_ws,
    const float* __restrict__ wo, const float* __restrict__ bo,
    const float* __restrict__ x, float* __restrict__ out) {
  __shared__ bf16_t slab[256 * 128];  // [row=d8*hw32][s128], slot16-XOR by hw&7
  const int bid = blockIdx.x;
  const int ht = bid & 7, dc = (bid >> 3) & 7, ch = (bid >> 6) & 1, b = bid >> 7;
  const int t = threadIdx.x, w = t >> 6, lane = t & 63;
  const int l16 = lane & 15, g = lane >> 4;
  const int mh = w >> 1, nh = w & 1;

  {
    const int d = t >> 5, hw = t & 31;
    const bf16_t* src = att_ws + ((size_t)((b * ND + dc * 8 + d) * NHW + ht * 32 + hw)) * NS;
    const int row = d * 32 + hw;
    #pragma unroll
    for (int j = 0; j < 16; ++j) {
      bf16x8 v8 = *(const bf16x8*)(src + j * 8);
      *(bf16x8*)&slab[row * NS + ((j ^ (hw & 7)) << 3)] = v8;
    }
  }
  __syncthreads();

  f32x4 acc[4][8] = {};
  #pragma unroll
  for (int kq = 0; kq < 4; ++kq) {
    bf16x8 af[4];
    #pragma unroll
    for (int mt = 0; mt < 4; ++mt) {
      int c = ch * 128 + mh * 64 + mt * 16 + l16;
      af[mt] = ldg_w8(wo + (size_t)c * NS + kq * 32 + g * 8);
    }
    #pragma unroll
    for (int nt = 0; nt < 8; ++nt) {
      int dl = nh * 4 + (nt >> 1);
      int hwl = (nt & 1) * 16 + l16;
      int row = dl * 32 + hwl;
      bf16x8 bfr = *(const bf16x8*)&slab[row * NS + (((kq * 4 + g) ^ (hwl & 7)) << 3)];
      #pragma unroll
      for (int mt = 0; mt < 4; ++mt)
        acc[mt][nt] = __builtin_amdgcn_mfma_f32_16x16x32_bf16(af[mt], bfr, acc[mt][nt], 0, 0, 0);
    }
  }

  #pragma unroll
  for (int mt = 0; mt < 4; ++mt) {
    #pragma unroll
    for (int r = 0; r < 4; ++r) {
      int c = ch * 128 + mh * 64 + mt * 16 + g * 4 + r;
      float bias = bo[c];
      #pragma unroll
      for (int nt = 0; nt < 8; ++nt) {
        int dg = dc * 8 + nh * 4 + (nt >> 1);
        int hwg = ht * 32 + (nt & 1) * 16 + l16;
        size_t gi = ((size_t)(b * NC + c) * ND + dg) * NHW + hwg;
        out[gi] = acc[mt][nt][r] + bias + x[gi];
      }
    }
  }
}

// ================= Fallback: round-1 fused kernel =================
struct SMemF {
  union {
    bf16_t xT[ND * NC];
    struct { bf16_t aT[ND * ND]; bf16_t attT[ND * NS]; } p2;
  } u;
  bf16_t kT[ND * NS];
  bf16_t qT[ND * NS];
  bf16_t vS[NS * ND];
};

__global__ __launch_bounds__(256) void attn_fused(
    const float* __restrict__ x,
    const float* __restrict__ wk, const float* __restrict__ bk,
    const float* __restrict__ wq, const float* __restrict__ bq,
    const float* __restrict__ wv, const float* __restrict__ bv,
    const float* __restrict__ wo, const float* __restrict__ bo,
    float* __restrict__ out) {
  __shared__ SMemF sm;
  const int gid = blockIdx.x;
  const int b = gid & 7;
  const int hw = gid >> 3;
  const int t = threadIdx.x;
  const int w = t >> 6;
  const int lane = t & 63;
  const int l16 = lane & 15;
  const int q4 = lane >> 4;
  const float* xb = x + (size_t)b * NC * ND * NHW + hw;
  {
    const int d = t & 63;
    const int cb = (t >> 6) * 64;
    for (int jj = 0; jj < 8; ++jj) {
      bf16x8 pk;
      #pragma unroll
      for (int e = 0; e < 8; ++e) {
        int c = cb + jj * 8 + e;
        pk[e] = (bf16_t)xb[(size_t)(c * ND + d) * NHW];
      }
      *(bf16x8*)&sm.u.xT[d * NC + swz(d, cb + jj * 8)] = pk;
    }
  }
  __syncthreads();
  {
    const int mat = w >> 1;
    const int sb = (w & 1) * 64;
    const float* wm = mat ? wq : wk;
    const float* bm = mat ? bq : bk;
    bf16_t* dst = mat ? sm.qT : sm.kT;
    f32x4 acc[4][4] = {};
    for (int ks = 0; ks < 8; ++ks) {
      const int kb = ks * 32 + q4 * 8;
      bf16x8 afr[4];
      #pragma unroll
      for (int mt = 0; mt < 4; ++mt) {
        int row = mt * 16 + l16;
        afr[mt] = *(const bf16x8*)&sm.u.xT[row * NC + swz(row, kb)];
      }
      #pragma unroll
      for (int st = 0; st < 4; ++st) {
        int s = sb + st * 16 + l16;
        bf16x8 bfr = ldg_w8(wm + s * NC + kb);
        #pragma unroll
        for (int mt = 0; mt < 4; ++mt)
          acc[mt][st] = __builtin_amdgcn_mfma_f32_16x16x32_bf16(afr[mt], bfr, acc[mt][st], 0, 0, 0);
      }
    }
    #pragma unroll
    for (int st = 0; st < 4; ++st) {
      int s = sb + st * 16 + l16;
      float bias = bm[s];
      #pragma unroll
      for (int mt = 0; mt < 4; ++mt) {
        #pragma unroll
        for (int r = 0; r < 4; ++r) {
          int d = mt * 16 + q4 * 4 + r;
          dst[d * NS + swz(d, s)] = (bf16_t)(acc[mt][st][r] + bias);
        }
      }
    }
  }
  {
    const int sb = w * 32;
    f32x4 acc[2][4] = {};
    for (int ks = 0; ks < 8; ++ks) {
      const int kb = ks * 32 + q4 * 8;
      bf16x8 afr[2];
      #pragma unroll
      for (int mt = 0; mt < 2; ++mt)
        afr[mt] = ldg_w8(wv + (sb + mt * 16 + l16) * NC + kb);
      #pragma unroll
      for (int nt = 0; nt < 4; ++nt) {
        int row = nt * 16 + l16;
        bf16x8 bfr = *(const bf16x8*)&sm.u.xT[row * NC + swz(row, kb)];
        #pragma unroll
        for (int mt = 0; mt < 2; ++mt)
          acc[mt][nt] = __builtin_amdgcn_mfma_f32_16x16x32_bf16(afr[mt], bfr, acc[mt][nt], 0, 0, 0);
      }
    }
    #pragma unroll
    for (int mt = 0; mt < 2; ++mt) {
      #pragma unroll
      for (int r = 0; r < 4; ++r) {
        int s = sb + mt * 16 + q4 * 4 + r;
        float bias = bv[s];
        #pragma unroll
        for (int nt = 0; nt < 4; ++nt) {
          int d = nt * 16 + l16;
          sm.vS[s * ND + swz(s, d)] = (bf16_t)(acc[mt][nt][r] + bias);
        }
      }
    }
  }
  __syncthreads();
  {
    f32x4 sacc[4] = {};
    for (int ks = 0; ks < 4; ++ks) {
      const int kb = ks * 32 + q4 * 8;
      int jrow = w * 16 + l16;
      bf16x8 bfr = *(const bf16x8*)&sm.qT[jrow * NS + swz(jrow, kb)];
      #pragma unroll
      for (int it = 0; it < 4; ++it) {
        int irow = it * 16 + l16;
        bf16x8 afr = *(const bf16x8*)&sm.kT[irow * NS + swz(irow, kb)];
        sacc[it] = __builtin_amdgcn_mfma_f32_16x16x32_bf16(afr, bfr, sacc[it], 0, 0, 0);
      }
    }
    const float scale = 0.088388347648318447f;
    float ps[16];
    float mx = -1e30f;
    #pragma unroll
    for (int it = 0; it < 4; ++it) {
      #pragma unroll
      for (int r = 0; r < 4; ++r) {
        float vv = sacc[it][r] * scale;
        ps[it * 4 + r] = vv;
        mx = fmaxf(mx, vv);
      }
    }
    mx = fmaxf(mx, __shfl_xor(mx, 16));
    mx = fmaxf(mx, __shfl_xor(mx, 32));
    float sum = 0.f;
    #pragma unroll
    for (int i = 0; i < 16; ++i) { ps[i] = __expf(ps[i] - mx); sum += ps[i]; }
    sum += __shfl_xor(sum, 16);
    sum += __shfl_xor(sum, 32);
    float inv = 1.f / sum;
    int j = w * 16 + l16;
    #pragma unroll
    for (int it = 0; it < 4; ++it) {
      bf16x4 pk;
      #pragma unroll
      for (int r = 0; r < 4; ++r) pk[r] = (bf16_t)(ps[it * 4 + r] * inv);
      *(bf16x4*)&sm.u.p2.aT[j * ND + swz(j, it * 16 + q4 * 4)] = pk;
    }
  }
  __syncthreads();
  {
    const int sb = w * 32;
    f32x4 acc[2][4] = {};
    #pragma unroll
    for (int ki = 0; ki < 2; ++ki) {
      const int kb = ki * 32 + q4 * 8;
      bf16x8 afr[2];
      #pragma unroll
      for (int mt = 0; mt < 2; ++mt) {
        int srow = sb + mt * 16 + l16;
        afr[mt] = *(const bf16x8*)&sm.vS[srow * ND + swz(srow, kb)];
      }
      #pragma unroll
      for (int nt = 0; nt < 4; ++nt) {
        int jrow = nt * 16 + l16;
        bf16x8 bfr = *(const bf16x8*)&sm.u.p2.aT[jrow * ND + swz(jrow, kb)];
        #pragma unroll
        for (int mt = 0; mt < 2; ++mt)
          acc[mt][nt] = __builtin_amdgcn_mfma_f32_16x16x32_bf16(afr[mt], bfr, acc[mt][nt], 0, 0, 0);
      }
    }
    #pragma unroll
    for (int nt = 0; nt < 4; ++nt) {
      int j = nt * 16 + l16;
      #pragma unroll
      for (int mt = 0; mt < 2; ++mt) {
        bf16x4 pk;
        #pragma unroll
        for (int r = 0; r < 4; ++r) pk[r] = (bf16_t)acc[mt][nt][r];
        *(bf16x4*)&sm.u.p2.attT[j * NS + swz(j, sb + mt * 16 + q4 * 4)] = pk;
      }
    }
  }
  __syncthreads();
  {
    const int cb = w * 64;
    f32x4 acc[4][4] = {};
    for (int ks = 0; ks < 4; ++ks) {
      const int kb = ks * 32 + q4 * 8;
      bf16x8 afr[4];
      #pragma unroll
      for (int mt = 0; mt < 4; ++mt)
        afr[mt] = ldg_w8(wo + (cb + mt * 16 + l16) * NS + kb);
      #pragma unroll
      for (int nt = 0; nt < 4; ++nt) {
        int jrow = nt * 16 + l16;
        bf16x8 bfr = *(const bf16x8*)&sm.u.p2.attT[jrow * NS + swz(jrow, kb)];
        #pragma unroll
        for (int mt = 0; mt < 4; ++mt)
          acc[mt][nt] = __builtin_amdgcn_mfma_f32_16x16x32_bf16(afr[mt], bfr, acc[mt][nt], 0, 0, 0);
      }
    }
    #pragma unroll
    for (int mt = 0; mt < 4; ++mt) {
      #pragma unroll
      for (int r = 0; r < 4; ++r) {
        int c = cb + mt * 16 + q4 * 4 + r;
        float bias = bo[c];
        #pragma unroll
        for (int nt = 0; nt < 4; ++nt) {
          int d = nt * 16 + l16;
          size_t gi = (size_t)(((b * NC + c) * ND + d) * NHW + hw);
          out[gi] = acc[mt][nt][r] + bias + x[gi];
        }
      }
    }
  }
}

extern "C" void kernel_launch(void* const* d_in, const int* in_sizes, int n_in,
                              void* d_out, int out_size, void* d_ws, size_t ws_size,
                              hipStream_t stream) {
  const float* x  = (const float*)d_in[0];
  const float* wk = (const float*)d_in[1];
  const float* bk = (const float*)d_in[2];
  const float* wq = (const float*)d_in[3];
  const float* bq = (const float*)d_in[4];
  const float* wv = (const float*)d_in[5];
  const float* bv = (const float*)d_in[6];
  const float* wo = (const float*)d_in[7];
  const float* bo = (const float*)d_in[8];
  float* out = (float*)d_out;

  // ws: [xT 64MiB | kT 32MiB | qT 32MiB | v 32MiB]; att reuses xT region.
  const size_t need = (size_t)167772160;
  if (ws_size >= need) {
    bf16_t* base = (bf16_t*)d_ws;
    bf16_t* xT  = base;                   // 33,554,432 el
    bf16_t* att = base;                   // reuse (xT dead after qkv_proj)
    bf16_t* kT  = base + 33554432;        // 16,777,216 el
    bf16_t* qT  = kT + 16777216;
    bf16_t* vv  = qT + 16777216;
    transpose_x<<<dim3(8192), dim3(256), 0, stream>>>(x, xT);
    qkv_proj<<<dim3(1536), dim3(256), 0, stream>>>(xT, wk, bk, wq, bq, wv, bv, kT, qT, vv);
    attn_core<<<dim3(2048), dim3(256), 0, stream>>>(kT, qT, vv, att);
    out_proj<<<dim3(1024), dim3(256), 0, stream>>>(att, wo, bo, x, out);
  } else {
    attn_fused<<<dim3(2048), dim3(256), 0, stream>>>(x, wk, bk, wq, bq, wv, bv, wo, bo, out);
  }
}

// Round 3
// 203.310 us; speedup vs baseline: 2.2977x; 1.2021x over previous
//
#include <hip/hip_runtime.h>
#include <hip/hip_bf16.h>

// 3-kernel pipeline:
//   T: x [b][c][d][hw] fp32 -> xT [b][d][hw][c] bf16; + convert weights to bf16
//   F: fused QKV projection + per-(b,hw) attention, one block per (b, 2hw),
//      k/q/v live only in LDS; att -> [b][d][hw][s] bf16
//   C: out-projection + bias + residual -> out [b][c][d][hw] fp32
// Fallback: round-1 fused kernel if workspace too small.

typedef __bf16 bf16_t;
typedef bf16_t bf16x8 __attribute__((ext_vector_type(8)));
typedef bf16_t bf16x4 __attribute__((ext_vector_type(4)));
typedef float  f32x4  __attribute__((ext_vector_type(4)));

#define NB   8
#define NC   256
#define ND   64
#define NHW  256
#define NS   128

#define MFMA16 __builtin_amdgcn_mfma_f32_16x16x32_bf16

__device__ __forceinline__ int swz(int row, int col) {
  return col ^ ((row & 7) << 3);
}

__device__ __forceinline__ bf16x8 pack8(float4 a, float4 b) {
  bf16x8 r;
  r[0] = (bf16_t)a.x; r[1] = (bf16_t)a.y; r[2] = (bf16_t)a.z; r[3] = (bf16_t)a.w;
  r[4] = (bf16_t)b.x; r[5] = (bf16_t)b.y; r[6] = (bf16_t)b.z; r[7] = (bf16_t)b.w;
  return r;
}

__device__ __forceinline__ bf16x8 ldg_w8(const float* p) {
  float4 a = *(const float4*)p;
  float4 b = *(const float4*)(p + 4);
  return pack8(a, b);
}

// ================= Kernel T: transpose x -> xT bf16; convert weights =========
// grid 8224: blocks [0,8192): 64c x 64hw tile per (b,d); [8192,8224): weights
__global__ __launch_bounds__(256) void transpose_x_w(
    const float* __restrict__ x,
    const float* __restrict__ wk, const float* __restrict__ wq,
    const float* __restrict__ wv, const float* __restrict__ wo,
    bf16_t* __restrict__ xT, bf16_t* __restrict__ wsW) {
  __shared__ bf16_t tile[64 * 72];   // [hw][c] pad to 72
  const int bid = blockIdx.x;
  if (bid >= 8192) {
    const int wid = bid - 8192;
    const int mat = wid >> 3;
    const float* src = (mat == 0) ? wk : (mat == 1) ? wq : (mat == 2) ? wv : wo;
    const int off = (wid & 7) * 4096 + threadIdx.x * 16;
    float4 a0 = *(const float4*)(src + off);
    float4 a1 = *(const float4*)(src + off + 4);
    float4 a2 = *(const float4*)(src + off + 8);
    float4 a3 = *(const float4*)(src + off + 12);
    *(bf16x8*)(wsW + mat * 32768 + off) = pack8(a0, a1);
    *(bf16x8*)(wsW + mat * 32768 + off + 8) = pack8(a2, a3);
    return;
  }
  const int ct = bid & 3, hwt = (bid >> 2) & 3;
  const int d = (bid >> 4) & 63, b = bid >> 10;
  const int c0 = ct * 64, hw0 = hwt * 64;
  const int t = threadIdx.x;
  const int hwq = t & 15, chi = t >> 4;

  #pragma unroll
  for (int q = 0; q < 4; ++q) {
    int c = q * 16 + chi;
    float4 v4 = *(const float4*)(x + ((size_t)((b * NC + c0 + c) * ND + d)) * NHW + hw0 + hwq * 4);
    tile[(hwq * 4 + 0) * 72 + c] = (bf16_t)v4.x;
    tile[(hwq * 4 + 1) * 72 + c] = (bf16_t)v4.y;
    tile[(hwq * 4 + 2) * 72 + c] = (bf16_t)v4.z;
    tile[(hwq * 4 + 3) * 72 + c] = (bf16_t)v4.w;
  }
  __syncthreads();
  #pragma unroll
  for (int i = 0; i < 2; ++i) {
    int idx = t + 256 * i;
    int hw = idx >> 3, q = idx & 7;
    bf16x8 v8 = *(const bf16x8*)&tile[hw * 72 + q * 8];
    *(bf16x8*)(xT + ((size_t)((b * ND + d) * NHW + hw0 + hw)) * NC + c0 + q * 8) = v8;
  }
}

// ================= Kernel F: fused QKV + attention =================
// grid 1024 = ht(128, 2hw each) * b(8); bid = ht*8 + b. 256 threads (4 waves).
// LDS 128 KB: xTl[128 n][128 c] (32K) | kT[2][64 d][128 s] (32K)
//             | qT (32K) | vS[2][128 s][64 d] (32K); aT[2][64][64] overlays xTl.
__global__ __launch_bounds__(256, 1) void qkv_attn(
    const bf16_t* __restrict__ xT, const bf16_t* __restrict__ wsW,
    const float* __restrict__ bk, const float* __restrict__ bq,
    const float* __restrict__ bv, bf16_t* __restrict__ att) {
  __shared__ bf16_t lds[65536];
  bf16_t* xTl = lds;            // 16384 el, [n][c] n = hwl*64+d (per 128-c slice)
  bf16_t* kT  = lds + 16384;    // [hw][d][s]
  bf16_t* qT  = lds + 32768;
  bf16_t* vS  = lds + 49152;    // [hw][s][d]
  bf16_t* aT  = lds;            // overlay: [hw][j][i], 8192 el

  const int bid = blockIdx.x;
  const int b = bid & 7, ht = bid >> 3;
  const int hw0 = ht * 2;
  const int t = threadIdx.x, w = t >> 6, lane = t & 63;
  const int l16 = lane & 15, g = lane >> 4;
  const int mh = w >> 1, nh = w & 1;

  const bf16_t* wkb = wsW;
  const bf16_t* wqb = wsW + 32768;
  const bf16_t* wvb = wsW + 65536;

  f32x4 acck[4][4] = {}, accq[4][4] = {}, accv[4][4] = {};

  for (int cc = 0; cc < 2; ++cc) {
    __syncthreads();
    // stage xT slice [128 n][128 c] (coalesced 256B runs), swizzled dest
    #pragma unroll
    for (int jj = 0; jj < 8; ++jj) {
      int slot = jj * 256 + t;
      int n = slot >> 4, cg = (slot & 15) * 8;
      int d = n & 63, hwl = n >> 6;
      bf16x8 v8 = *(const bf16x8*)(xT + ((size_t)((b * ND + d) * NHW + hw0 + hwl)) * NC + cc * 128 + cg);
      *(bf16x8*)&xTl[n * 128 + swz(n, cg)] = v8;
    }
    __syncthreads();
    #pragma unroll
    for (int kf = 0; kf < 4; ++kf) {
      const int kb = kf * 32 + g * 8;       // c within slice
      const int kg = cc * 128 + kb;         // c global
      bf16x8 bfr[4], afk[4], afq[4], vA[4], vB[4];
      #pragma unroll
      for (int i = 0; i < 4; ++i) {
        int nB = nh * 64 + i * 16 + l16;    // B rows (n) for k,q
        bfr[i] = *(const bf16x8*)&xTl[nB * 128 + swz(nB, kb)];
        int sA = mh * 64 + i * 16 + l16;    // A rows (s) for k,q
        afk[i] = *(const bf16x8*)(wkb + (size_t)sA * NC + kg);
        afq[i] = *(const bf16x8*)(wqb + (size_t)sA * NC + kg);
      }
      #pragma unroll
      for (int nf = 0; nf < 4; ++nf)
        #pragma unroll
        for (int mt = 0; mt < 4; ++mt)
          acck[mt][nf] = MFMA16(afk[mt], bfr[nf], acck[mt][nf], 0, 0, 0);
      #pragma unroll
      for (int nf = 0; nf < 4; ++nf)
        #pragma unroll
        for (int mt = 0; mt < 4; ++mt)
          accq[mt][nf] = MFMA16(afq[mt], bfr[nf], accq[mt][nf], 0, 0, 0);
      #pragma unroll
      for (int i = 0; i < 4; ++i) {
        int nA = mh * 64 + i * 16 + l16;    // A rows (n) for v
        vA[i] = *(const bf16x8*)&xTl[nA * 128 + swz(nA, kb)];
        int sB = nh * 64 + i * 16 + l16;    // B rows (s) for v
        vB[i] = *(const bf16x8*)(wvb + (size_t)sB * NC + kg);
      }
      #pragma unroll
      for (int nf = 0; nf < 4; ++nf)
        #pragma unroll
        for (int mt = 0; mt < 4; ++mt)
          accv[mt][nf] = MFMA16(vA[mt], vB[nf], accv[mt][nf], 0, 0, 0);
    }
  }

  // ---- epilogue: k,q -> kT/qT [hw][d][s]; v -> vS [hw][s][d] ----
  #pragma unroll
  for (int mt = 0; mt < 4; ++mt) {
    int s0 = mh * 64 + mt * 16 + g * 4;
    float4 b4k = *(const float4*)(bk + s0);
    float4 b4q = *(const float4*)(bq + s0);
    #pragma unroll
    for (int nf = 0; nf < 4; ++nf) {
      int d = nf * 16 + l16;
      int el = nh * 8192 + d * 128 + swz(d, s0);
      bf16x4 pk, pq;
      pk[0] = (bf16_t)(acck[mt][nf][0] + b4k.x);
      pk[1] = (bf16_t)(acck[mt][nf][1] + b4k.y);
      pk[2] = (bf16_t)(acck[mt][nf][2] + b4k.z);
      pk[3] = (bf16_t)(acck[mt][nf][3] + b4k.w);
      pq[0] = (bf16_t)(accq[mt][nf][0] + b4q.x);
      pq[1] = (bf16_t)(accq[mt][nf][1] + b4q.y);
      pq[2] = (bf16_t)(accq[mt][nf][2] + b4q.z);
      pq[3] = (bf16_t)(accq[mt][nf][3] + b4q.w);
      *(bf16x4*)&kT[el] = pk;
      *(bf16x4*)&qT[el] = pq;
    }
  }
  #pragma unroll
  for (int nf = 0; nf < 4; ++nf) {
    int s = nh * 64 + nf * 16 + l16;
    float bvs = bv[s];
    #pragma unroll
    for (int mt = 0; mt < 4; ++mt) {
      int d0 = mt * 16 + g * 4;
      bf16x4 pv;
      pv[0] = (bf16_t)(accv[mt][nf][0] + bvs);
      pv[1] = (bf16_t)(accv[mt][nf][1] + bvs);
      pv[2] = (bf16_t)(accv[mt][nf][2] + bvs);
      pv[3] = (bf16_t)(accv[mt][nf][3] + bvs);
      *(bf16x4*)&vS[mh * 8192 + s * 64 + (d0 ^ ((s & 7) << 3))] = pv;
    }
  }
  __syncthreads();

  // ---- attention: waves (0,1)->hw0, (2,3)->hw1 ----
  const int ha = w >> 1, wp = w & 1;

  // scores[i][j] = sum_s k[s,i] q[s,j]
  f32x4 sacc[4][2] = {};
  #pragma unroll
  for (int ks = 0; ks < 4; ++ks) {
    int kb = ks * 32 + g * 8;
    bf16x8 bq2[2];
    #pragma unroll
    for (int jt = 0; jt < 2; ++jt) {
      int j = wp * 32 + jt * 16 + l16;
      bq2[jt] = *(const bf16x8*)&qT[ha * 8192 + j * 128 + swz(j, kb)];
    }
    #pragma unroll
    for (int it = 0; it < 4; ++it) {
      int i = it * 16 + l16;
      bf16x8 af = *(const bf16x8*)&kT[ha * 8192 + i * 128 + swz(i, kb)];
      #pragma unroll
      for (int jt = 0; jt < 2; ++jt)
        sacc[it][jt] = MFMA16(af, bq2[jt], sacc[it][jt], 0, 0, 0);
    }
  }
  // softmax over i, per jt; write aT[ha][j][i]
  const float scale = 0.088388347648318447f;  // 1/sqrt(128)
  #pragma unroll
  for (int jt = 0; jt < 2; ++jt) {
    float ps[16];
    float mx = -1e30f;
    #pragma unroll
    for (int it = 0; it < 4; ++it)
      #pragma unroll
      for (int r = 0; r < 4; ++r) {
        float vv = sacc[it][jt][r] * scale;
        ps[it * 4 + r] = vv;
        mx = fmaxf(mx, vv);
      }
    mx = fmaxf(mx, __shfl_xor(mx, 16));
    mx = fmaxf(mx, __shfl_xor(mx, 32));
    float sum = 0.f;
    #pragma unroll
    for (int i = 0; i < 16; ++i) { ps[i] = __expf(ps[i] - mx); sum += ps[i]; }
    sum += __shfl_xor(sum, 16);
    sum += __shfl_xor(sum, 32);
    float inv = 1.f / sum;
    int j = wp * 32 + jt * 16 + l16;
    #pragma unroll
    for (int it = 0; it < 4; ++it) {
      bf16x4 pk;
      #pragma unroll
      for (int r = 0; r < 4; ++r) pk[r] = (bf16_t)(ps[it * 4 + r] * inv);
      *(bf16x4*)&aT[ha * 4096 + j * 64 + ((it * 16 + g * 4) ^ ((j & 7) << 3))] = pk;
    }
  }
  __syncthreads();

  // att[s][j] = sum_i v[s,i] a[i,j]; store -> att[b][d=j][hw][s]
  f32x4 pacc[4][4] = {};
  #pragma unroll
  for (int ki = 0; ki < 2; ++ki) {
    int kb = ki * 32 + g * 8;
    bf16x8 afv[4], bfa[4];
    #pragma unroll
    for (int mt = 0; mt < 4; ++mt) {
      int s = wp * 64 + mt * 16 + l16;
      afv[mt] = *(const bf16x8*)&vS[ha * 8192 + s * 64 + (kb ^ ((s & 7) << 3))];
    }
    #pragma unroll
    for (int nt = 0; nt < 4; ++nt) {
      int j = nt * 16 + l16;
      bfa[nt] = *(const bf16x8*)&aT[ha * 4096 + j * 64 + (kb ^ ((j & 7) << 3))];
    }
    #pragma unroll
    for (int nt = 0; nt < 4; ++nt)
      #pragma unroll
      for (int mt = 0; mt < 4; ++mt)
        pacc[mt][nt] = MFMA16(afv[mt], bfa[nt], pacc[mt][nt], 0, 0, 0);
  }
  #pragma unroll
  for (int mt = 0; mt < 4; ++mt) {
    int s0 = wp * 64 + mt * 16 + g * 4;
    #pragma unroll
    for (int nt = 0; nt < 4; ++nt) {
      int d = nt * 16 + l16;
      bf16x4 pk;
      #pragma unroll
      for (int r = 0; r < 4; ++r) pk[r] = (bf16_t)pacc[mt][nt][r];
      *(bf16x4*)(att + ((size_t)((b * ND + d) * NHW + hw0 + ha)) * NS + s0) = pk;
    }
  }
}

// ================= Kernel C: out projection + residual =================
// grid 1024 = 8(ht of 32hw) * 8(dc of 8d) * 2(ch of 128c) * 8(b)
__global__ __launch_bounds__(256, 2) void out_proj(
    const bf16_t* __restrict__ att_ws,
    const bf16_t* __restrict__ wob, const float* __restrict__ bo,
    const float* __restrict__ x, float* __restrict__ out) {
  __shared__ bf16_t slab[256 * 128];  // [row=d8*hw32][s128], slot16-XOR by hw&7
  const int bid = blockIdx.x;
  const int ht = bid & 7, dc = (bid >> 3) & 7, ch = (bid >> 6) & 1, b = bid >> 7;
  const int t = threadIdx.x, w = t >> 6, lane = t & 63;
  const int l16 = lane & 15, g = lane >> 4;
  const int mh = w >> 1, nh = w & 1;

  {
    const int d = t >> 5, hw = t & 31;
    const bf16_t* src = att_ws + ((size_t)((b * ND + dc * 8 + d) * NHW + ht * 32 + hw)) * NS;
    const int row = d * 32 + hw;
    #pragma unroll
    for (int j = 0; j < 16; ++j) {
      bf16x8 v8 = *(const bf16x8*)(src + j * 8);
      *(bf16x8*)&slab[row * NS + ((j ^ (hw & 7)) << 3)] = v8;
    }
  }
  __syncthreads();

  f32x4 acc[4][8] = {};
  #pragma unroll
  for (int kq = 0; kq < 4; ++kq) {
    bf16x8 af[4];
    #pragma unroll
    for (int mt = 0; mt < 4; ++mt) {
      int c = ch * 128 + mh * 64 + mt * 16 + l16;
      af[mt] = *(const bf16x8*)(wob + (size_t)c * NS + kq * 32 + g * 8);
    }
    #pragma unroll
    for (int nt = 0; nt < 8; ++nt) {
      int dl = nh * 4 + (nt >> 1);
      int hwl = (nt & 1) * 16 + l16;
      int row = dl * 32 + hwl;
      bf16x8 bfr = *(const bf16x8*)&slab[row * NS + (((kq * 4 + g) ^ (hwl & 7)) << 3)];
      #pragma unroll
      for (int mt = 0; mt < 4; ++mt)
        acc[mt][nt] = MFMA16(af[mt], bfr, acc[mt][nt], 0, 0, 0);
    }
  }

  #pragma unroll
  for (int mt = 0; mt < 4; ++mt) {
    #pragma unroll
    for (int r = 0; r < 4; ++r) {
      int c = ch * 128 + mh * 64 + mt * 16 + g * 4 + r;
      float bias = bo[c];
      #pragma unroll
      for (int nt = 0; nt < 8; ++nt) {
        int dg = dc * 8 + nh * 4 + (nt >> 1);
        int hwg = ht * 32 + (nt & 1) * 16 + l16;
        size_t gi = ((size_t)(b * NC + c) * ND + dg) * NHW + hwg;
        out[gi] = acc[mt][nt][r] + bias + x[gi];
      }
    }
  }
}

// ================= Fallback: round-1 fused kernel =================
struct SMemF {
  union {
    bf16_t xT[ND * NC];
    struct { bf16_t aT[ND * ND]; bf16_t attT[ND * NS]; } p2;
  } u;
  bf16_t kT[ND * NS];
  bf16_t qT[ND * NS];
  bf16_t vS[NS * ND];
};

__global__ __launch_bounds__(256) void attn_fused(
    const float* __restrict__ x,
    const float* __restrict__ wk, const float* __restrict__ bk,
    const float* __restrict__ wq, const float* __restrict__ bq,
    const float* __restrict__ wv, const float* __restrict__ bv,
    const float* __restrict__ wo, const float* __restrict__ bo,
    float* __restrict__ out) {
  __shared__ SMemF sm;
  const int gid = blockIdx.x;
  const int b = gid & 7;
  const int hw = gid >> 3;
  const int t = threadIdx.x;
  const int w = t >> 6;
  const int lane = t & 63;
  const int l16 = lane & 15;
  const int q4 = lane >> 4;
  const float* xb = x + (size_t)b * NC * ND * NHW + hw;
  {
    const int d = t & 63;
    const int cb = (t >> 6) * 64;
    for (int jj = 0; jj < 8; ++jj) {
      bf16x8 pk;
      #pragma unroll
      for (int e = 0; e < 8; ++e) {
        int c = cb + jj * 8 + e;
        pk[e] = (bf16_t)xb[(size_t)(c * ND + d) * NHW];
      }
      *(bf16x8*)&sm.u.xT[d * NC + swz(d, cb + jj * 8)] = pk;
    }
  }
  __syncthreads();
  {
    const int mat = w >> 1;
    const int sb = (w & 1) * 64;
    const float* wm = mat ? wq : wk;
    const float* bm = mat ? bq : bk;
    bf16_t* dst = mat ? sm.qT : sm.kT;
    f32x4 acc[4][4] = {};
    for (int ks = 0; ks < 8; ++ks) {
      const int kb = ks * 32 + q4 * 8;
      bf16x8 afr[4];
      #pragma unroll
      for (int mt = 0; mt < 4; ++mt) {
        int row = mt * 16 + l16;
        afr[mt] = *(const bf16x8*)&sm.u.xT[row * NC + swz(row, kb)];
      }
      #pragma unroll
      for (int st = 0; st < 4; ++st) {
        int s = sb + st * 16 + l16;
        bf16x8 bfr = ldg_w8(wm + s * NC + kb);
        #pragma unroll
        for (int mt = 0; mt < 4; ++mt)
          acc[mt][st] = MFMA16(afr[mt], bfr, acc[mt][st], 0, 0, 0);
      }
    }
    #pragma unroll
    for (int st = 0; st < 4; ++st) {
      int s = sb + st * 16 + l16;
      float bias = bm[s];
      #pragma unroll
      for (int mt = 0; mt < 4; ++mt) {
        #pragma unroll
        for (int r = 0; r < 4; ++r) {
          int d = mt * 16 + q4 * 4 + r;
          dst[d * NS + swz(d, s)] = (bf16_t)(acc[mt][st][r] + bias);
        }
      }
    }
  }
  {
    const int sb = w * 32;
    f32x4 acc[2][4] = {};
    for (int ks = 0; ks < 8; ++ks) {
      const int kb = ks * 32 + q4 * 8;
      bf16x8 afr[2];
      #pragma unroll
      for (int mt = 0; mt < 2; ++mt)
        afr[mt] = ldg_w8(wv + (sb + mt * 16 + l16) * NC + kb);
      #pragma unroll
      for (int nt = 0; nt < 4; ++nt) {
        int row = nt * 16 + l16;
        bf16x8 bfr = *(const bf16x8*)&sm.u.xT[row * NC + swz(row, kb)];
        #pragma unroll
        for (int mt = 0; mt < 2; ++mt)
          acc[mt][nt] = MFMA16(afr[mt], bfr, acc[mt][nt], 0, 0, 0);
      }
    }
    #pragma unroll
    for (int mt = 0; mt < 2; ++mt) {
      #pragma unroll
      for (int r = 0; r < 4; ++r) {
        int s = sb + mt * 16 + q4 * 4 + r;
        float bias = bv[s];
        #pragma unroll
        for (int nt = 0; nt < 4; ++nt) {
          int d = nt * 16 + l16;
          sm.vS[s * ND + swz(s, d)] = (bf16_t)(acc[mt][nt][r] + bias);
        }
      }
    }
  }
  __syncthreads();
  {
    f32x4 sacc[4] = {};
    for (int ks = 0; ks < 4; ++ks) {
      const int kb = ks * 32 + q4 * 8;
      int jrow = w * 16 + l16;
      bf16x8 bfr = *(const bf16x8*)&sm.qT[jrow * NS + swz(jrow, kb)];
      #pragma unroll
      for (int it = 0; it < 4; ++it) {
        int irow = it * 16 + l16;
        bf16x8 afr = *(const bf16x8*)&sm.kT[irow * NS + swz(irow, kb)];
        sacc[it] = MFMA16(afr, bfr, sacc[it], 0, 0, 0);
      }
    }
    const float scale = 0.088388347648318447f;
    float ps[16];
    float mx = -1e30f;
    #pragma unroll
    for (int it = 0; it < 4; ++it) {
      #pragma unroll
      for (int r = 0; r < 4; ++r) {
        float vv = sacc[it][r] * scale;
        ps[it * 4 + r] = vv;
        mx = fmaxf(mx, vv);
      }
    }
    mx = fmaxf(mx, __shfl_xor(mx, 16));
    mx = fmaxf(mx, __shfl_xor(mx, 32));
    float sum = 0.f;
    #pragma unroll
    for (int i = 0; i < 16; ++i) { ps[i] = __expf(ps[i] - mx); sum += ps[i]; }
    sum += __shfl_xor(sum, 16);
    sum += __shfl_xor(sum, 32);
    float inv = 1.f / sum;
    int j = w * 16 + l16;
    #pragma unroll
    for (int it = 0; it < 4; ++it) {
      bf16x4 pk;
      #pragma unroll
      for (int r = 0; r < 4; ++r) pk[r] = (bf16_t)(ps[it * 4 + r] * inv);
      *(bf16x4*)&sm.u.p2.aT[j * ND + swz(j, it * 16 + q4 * 4)] = pk;
    }
  }
  __syncthreads();
  {
    const int sb = w * 32;
    f32x4 acc[2][4] = {};
    #pragma unroll
    for (int ki = 0; ki < 2; ++ki) {
      const int kb = ki * 32 + q4 * 8;
      bf16x8 afr[2];
      #pragma unroll
      for (int mt = 0; mt < 2; ++mt) {
        int srow = sb + mt * 16 + l16;
        afr[mt] = *(const bf16x8*)&sm.vS[srow * ND + swz(srow, kb)];
      }
      #pragma unroll
      for (int nt = 0; nt < 4; ++nt) {
        int jrow = nt * 16 + l16;
        bf16x8 bfr = *(const bf16x8*)&sm.u.p2.aT[jrow * ND + swz(jrow, kb)];
        #pragma unroll
        for (int mt = 0; mt < 2; ++mt)
          acc[mt][nt] = MFMA16(afr[mt], bfr, acc[mt][nt], 0, 0, 0);
      }
    }
    #pragma unroll
    for (int nt = 0; nt < 4; ++nt) {
      int j = nt * 16 + l16;
      #pragma unroll
      for (int mt = 0; mt < 2; ++mt) {
        bf16x4 pk;
        #pragma unroll
        for (int r = 0; r < 4; ++r) pk[r] = (bf16_t)acc[mt][nt][r];
        *(bf16x4*)&sm.u.p2.attT[j * NS + swz(j, sb + mt * 16 + q4 * 4)] = pk;
      }
    }
  }
  __syncthreads();
  {
    const int cb = w * 64;
    f32x4 acc[4][4] = {};
    for (int ks = 0; ks < 4; ++ks) {
      const int kb = ks * 32 + q4 * 8;
      bf16x8 afr[4];
      #pragma unroll
      for (int mt = 0; mt < 4; ++mt)
        afr[mt] = ldg_w8(wo + (cb + mt * 16 + l16) * NS + kb);
      #pragma unroll
      for (int nt = 0; nt < 4; ++nt) {
        int jrow = nt * 16 + l16;
        bf16x8 bfr = *(const bf16x8*)&sm.u.p2.attT[jrow * NS + swz(jrow, kb)];
        #pragma unroll
        for (int mt = 0; mt < 4; ++mt)
          acc[mt][nt] = MFMA16(afr[mt], bfr, acc[mt][nt], 0, 0, 0);
      }
    }
    #pragma unroll
    for (int mt = 0; mt < 4; ++mt) {
      #pragma unroll
      for (int r = 0; r < 4; ++r) {
        int c = cb + mt * 16 + q4 * 4 + r;
        float bias = bo[c];
        #pragma unroll
        for (int nt = 0; nt < 4; ++nt) {
          int d = nt * 16 + l16;
          size_t gi = (size_t)(((b * NC + c) * ND + d) * NHW + hw);
          out[gi] = acc[mt][nt][r] + bias + x[gi];
        }
      }
    }
  }
}

extern "C" void kernel_launch(void* const* d_in, const int* in_sizes, int n_in,
                              void* d_out, int out_size, void* d_ws, size_t ws_size,
                              hipStream_t stream) {
  const float* x  = (const float*)d_in[0];
  const float* wk = (const float*)d_in[1];
  const float* bk = (const float*)d_in[2];
  const float* wq = (const float*)d_in[3];
  const float* bq = (const float*)d_in[4];
  const float* wv = (const float*)d_in[5];
  const float* bv = (const float*)d_in[6];
  const float* wo = (const float*)d_in[7];
  const float* bo = (const float*)d_in[8];
  float* out = (float*)d_out;

  // ws: [weights bf16 131072 el | xT 33554432 el | att 16777216 el]
  const size_t need = (size_t)(131072 + 33554432 + 16777216) * 2;
  if (ws_size >= need) {
    bf16_t* wsW = (bf16_t*)d_ws;
    bf16_t* xT  = wsW + 131072;
    bf16_t* att = xT + 33554432;
    transpose_x_w<<<dim3(8224), dim3(256), 0, stream>>>(x, wk, wq, wv, wo, xT, wsW);
    qkv_attn<<<dim3(1024), dim3(256), 0, stream>>>(xT, wsW, bk, bq, bv, att);
    out_proj<<<dim3(1024), dim3(256), 0, stream>>>(att, wsW + 98304, bo, x, out);
  } else {
    attn_fused<<<dim3(2048), dim3(256), 0, stream>>>(x, wk, bk, wq, bq, wv, bv, wo, bo, out);
  }
}

// Round 4
// 160.165 us; speedup vs baseline: 2.9167x; 1.2694x over previous
//
#include <hip/hip_runtime.h>
#include <hip/hip_bf16.h>

// 3-kernel pipeline:
//   T: x [b][c][d][hw] fp32 -> xT [b][d][hw][c] bf16; weights -> fragmented bf16
//      wF layout: [c>>3][s][c&7] so MFMA fragments are 256B-coalesced runs.
//   F: fused QKV + per-(b,hw) attention, one block per (b,hw), grid 2048,
//      LDS 80KB -> 2 blocks/CU (2 waves/SIMD). att -> [b][d][hw][s] bf16.
//   C: out-projection + bias + residual -> out [b][c][d][hw] fp32
// Fallback: round-1 fused kernel if workspace too small.

typedef __bf16 bf16_t;
typedef bf16_t bf16x8 __attribute__((ext_vector_type(8)));
typedef bf16_t bf16x4 __attribute__((ext_vector_type(4)));
typedef float  f32x4  __attribute__((ext_vector_type(4)));

#define NB   8
#define NC   256
#define ND   64
#define NHW  256
#define NS   128

#define MFMA16 __builtin_amdgcn_mfma_f32_16x16x32_bf16

__device__ __forceinline__ int swz(int row, int col) {
  return col ^ ((row & 7) << 3);
}

__device__ __forceinline__ bf16x8 pack8(float4 a, float4 b) {
  bf16x8 r;
  r[0] = (bf16_t)a.x; r[1] = (bf16_t)a.y; r[2] = (bf16_t)a.z; r[3] = (bf16_t)a.w;
  r[4] = (bf16_t)b.x; r[5] = (bf16_t)b.y; r[6] = (bf16_t)b.z; r[7] = (bf16_t)b.w;
  return r;
}

__device__ __forceinline__ bf16x8 ldg_w8(const float* p) {
  float4 a = *(const float4*)p;
  float4 b = *(const float4*)(p + 4);
  return pack8(a, b);
}

// ================= Kernel T: transpose x -> xT bf16; fragment weights ========
// grid 8224: [0,8192): 64c x 64hw tile per (b,d); [8192,8224): weights
__global__ __launch_bounds__(256) void transpose_x_w(
    const float* __restrict__ x,
    const float* __restrict__ wk, const float* __restrict__ wq,
    const float* __restrict__ wv, const float* __restrict__ wo,
    bf16_t* __restrict__ xT, bf16_t* __restrict__ wsW) {
  __shared__ bf16_t tile[64 * 72];   // [hw][c] pad to 72
  const int bid = blockIdx.x;
  if (bid >= 8192) {
    const int wid = bid - 8192;
    const int mat = wid >> 3, sub = wid & 7;
    const int t = threadIdx.x;
    if (mat < 3) {
      // wk/wq/wv [128 s][256 c] -> frag [32 cg][128 s][8]
      const float* src = (mat == 0) ? wk : (mat == 1) ? wq : wv;
      bf16_t* dst = wsW + mat * 32768;
      int s = sub * 16 + (t >> 4), c0 = (t & 15) * 16;
      const float* p = src + s * NC + c0;
      float4 a0 = *(const float4*)p, a1 = *(const float4*)(p + 4);
      float4 a2 = *(const float4*)(p + 8), a3 = *(const float4*)(p + 12);
      *(bf16x8*)(dst + (c0 >> 3) * 1024 + s * 8)       = pack8(a0, a1);
      *(bf16x8*)(dst + ((c0 >> 3) + 1) * 1024 + s * 8) = pack8(a2, a3);
    } else {
      // wo [256 c][128 s] -> frag [16 sg][256 c][8]
      bf16_t* dst = wsW + 98304;
      int c = sub * 32 + (t >> 3), sc0 = (t & 7) * 16;
      const float* p = wo + c * NS + sc0;
      float4 a0 = *(const float4*)p, a1 = *(const float4*)(p + 4);
      float4 a2 = *(const float4*)(p + 8), a3 = *(const float4*)(p + 12);
      *(bf16x8*)(dst + (sc0 >> 3) * 2048 + c * 8)       = pack8(a0, a1);
      *(bf16x8*)(dst + ((sc0 >> 3) + 1) * 2048 + c * 8) = pack8(a2, a3);
    }
    return;
  }
  const int ct = bid & 3, hwt = (bid >> 2) & 3;
  const int d = (bid >> 4) & 63, b = bid >> 10;
  const int c0 = ct * 64, hw0 = hwt * 64;
  const int t = threadIdx.x;
  const int hwq = t & 15, chi = t >> 4;

  #pragma unroll
  for (int q = 0; q < 4; ++q) {
    int c = q * 16 + chi;
    float4 v4 = *(const float4*)(x + ((size_t)((b * NC + c0 + c) * ND + d)) * NHW + hw0 + hwq * 4);
    tile[(hwq * 4 + 0) * 72 + c] = (bf16_t)v4.x;
    tile[(hwq * 4 + 1) * 72 + c] = (bf16_t)v4.y;
    tile[(hwq * 4 + 2) * 72 + c] = (bf16_t)v4.z;
    tile[(hwq * 4 + 3) * 72 + c] = (bf16_t)v4.w;
  }
  __syncthreads();
  #pragma unroll
  for (int i = 0; i < 2; ++i) {
    int idx = t + 256 * i;
    int hw = idx >> 3, q = idx & 7;
    bf16x8 v8 = *(const bf16x8*)&tile[hw * 72 + q * 8];
    *(bf16x8*)(xT + ((size_t)((b * ND + d) * NHW + hw0 + hw)) * NC + c0 + q * 8) = v8;
  }
}

// ================= Kernel F: fused QKV + attention =================
// grid 2048 = (hw,b); 256 threads (4 waves); LDS 80KB -> 2 blocks/CU.
__global__ __launch_bounds__(256, 2) void qkv_attn2(
    const bf16_t* __restrict__ xT, const bf16_t* __restrict__ wsW,
    const float* __restrict__ bk, const float* __restrict__ bq,
    const float* __restrict__ bv, bf16_t* __restrict__ att) {
  __shared__ struct {
    union {
      bf16_t xTl[ND * NC];                       // 32KB [d][c] swz
      struct {
        bf16_t aT[ND * ND];                      // 8KB [j][i] swz
        bf16_t attT[ND * NS];                    // 16KB [d][s] swz
      } p2;
    } u;
    bf16_t kT[ND * NS];                          // 16KB [d][s] swz
    bf16_t qT[ND * NS];                          // 16KB
    bf16_t vS[NS * ND];                          // 16KB [s][d] swz
  } sm;
  const int gid = blockIdx.x;
  const int b = gid & 7, hw = gid >> 3;
  const int t = threadIdx.x, w = t >> 6, lane = t & 63;
  const int l16 = lane & 15, q4 = lane >> 4;

  const bf16_t* wkF = wsW;
  const bf16_t* wqF = wsW + 32768;
  const bf16_t* wvF = wsW + 65536;

  // ---- stage xT[b][*][hw][*] -> xTl[d][c] (coalesced 512B rows) ----
  #pragma unroll
  for (int jj = 0; jj < 8; ++jj) {
    int id = jj * 256 + t;
    int d = id >> 5, cg = (id & 31) * 8;
    bf16x8 v8 = *(const bf16x8*)(xT + ((size_t)((b * ND + d) * NHW + hw)) * NC + cg);
    *(bf16x8*)&sm.u.xTl[d * NC + swz(d, cg)] = v8;
  }
  __syncthreads();

  // ---- K,Q: waves 0,1 -> K (s-halves); waves 2,3 -> Q ----
  // A = W rows (m=s, frag layout, coalesced), B = xTl (n=d). C: row=s, col=d.
  {
    const int mat = w >> 1;
    const int sb = (w & 1) * 64;
    const bf16_t* wm = mat ? wqF : wkF;
    const float* bm = mat ? bq : bk;
    bf16_t* dst = mat ? sm.qT : sm.kT;
    f32x4 acc[4][4] = {};
    for (int ks = 0; ks < 8; ++ks) {
      const int kb = ks * 32 + q4 * 8;
      bf16x8 afr[4];
      #pragma unroll
      for (int mt = 0; mt < 4; ++mt) {
        int s = sb + mt * 16 + l16;
        afr[mt] = *(const bf16x8*)(wm + (kb >> 3) * 1024 + s * 8);
      }
      #pragma unroll
      for (int nt = 0; nt < 4; ++nt) {
        int row = nt * 16 + l16;
        bf16x8 bfr = *(const bf16x8*)&sm.u.xTl[row * NC + swz(row, kb)];
        #pragma unroll
        for (int mt = 0; mt < 4; ++mt)
          acc[mt][nt] = MFMA16(afr[mt], bfr, acc[mt][nt], 0, 0, 0);
      }
    }
    #pragma unroll
    for (int mt = 0; mt < 4; ++mt) {
      int s0 = sb + mt * 16 + q4 * 4;
      float4 b4 = *(const float4*)(bm + s0);
      #pragma unroll
      for (int nt = 0; nt < 4; ++nt) {
        int d = nt * 16 + l16;
        bf16x4 pk;
        pk[0] = (bf16_t)(acc[mt][nt][0] + b4.x);
        pk[1] = (bf16_t)(acc[mt][nt][1] + b4.y);
        pk[2] = (bf16_t)(acc[mt][nt][2] + b4.z);
        pk[3] = (bf16_t)(acc[mt][nt][3] + b4.w);
        *(bf16x4*)&dst[d * NS + swz(d, s0)] = pk;
      }
    }
  }

  // ---- V: A = xTl (m=d), B = Wv rows (n=s, frag). C: row=d, col=s ----
  {
    const int sb = w * 32;
    f32x4 acc[4][2] = {};
    for (int ks = 0; ks < 8; ++ks) {
      const int kb = ks * 32 + q4 * 8;
      bf16x8 afr[4], bfr[2];
      #pragma unroll
      for (int mt = 0; mt < 4; ++mt) {
        int row = mt * 16 + l16;
        afr[mt] = *(const bf16x8*)&sm.u.xTl[row * NC + swz(row, kb)];
      }
      #pragma unroll
      for (int nt = 0; nt < 2; ++nt) {
        int s = sb + nt * 16 + l16;
        bfr[nt] = *(const bf16x8*)(wvF + (kb >> 3) * 1024 + s * 8);
      }
      #pragma unroll
      for (int nt = 0; nt < 2; ++nt)
        #pragma unroll
        for (int mt = 0; mt < 4; ++mt)
          acc[mt][nt] = MFMA16(afr[mt], bfr[nt], acc[mt][nt], 0, 0, 0);
    }
    #pragma unroll
    for (int nt = 0; nt < 2; ++nt) {
      int s = sb + nt * 16 + l16;
      float bvs = bv[s];
      #pragma unroll
      for (int mt = 0; mt < 4; ++mt) {
        int d0 = mt * 16 + q4 * 4;
        bf16x4 pv;
        pv[0] = (bf16_t)(acc[mt][nt][0] + bvs);
        pv[1] = (bf16_t)(acc[mt][nt][1] + bvs);
        pv[2] = (bf16_t)(acc[mt][nt][2] + bvs);
        pv[3] = (bf16_t)(acc[mt][nt][3] + bvs);
        *(bf16x4*)&sm.vS[s * ND + (d0 ^ ((s & 7) << 3))] = pv;
      }
    }
  }
  __syncthreads();

  // ---- scores[i][j] = sum_s kT[i][s] qT[j][s]; softmax over i -> aT[j][i] ----
  {
    f32x4 sacc[4] = {};
    for (int ks = 0; ks < 4; ++ks) {
      const int kb = ks * 32 + q4 * 8;
      int jrow = w * 16 + l16;
      bf16x8 bfr = *(const bf16x8*)&sm.qT[jrow * NS + swz(jrow, kb)];
      #pragma unroll
      for (int it = 0; it < 4; ++it) {
        int irow = it * 16 + l16;
        bf16x8 afr = *(const bf16x8*)&sm.kT[irow * NS + swz(irow, kb)];
        sacc[it] = MFMA16(afr, bfr, sacc[it], 0, 0, 0);
      }
    }
    const float scale = 0.088388347648318447f;  // 1/sqrt(128)
    float ps[16];
    float mx = -1e30f;
    #pragma unroll
    for (int it = 0; it < 4; ++it)
      #pragma unroll
      for (int r = 0; r < 4; ++r) {
        float vv = sacc[it][r] * scale;
        ps[it * 4 + r] = vv;
        mx = fmaxf(mx, vv);
      }
    mx = fmaxf(mx, __shfl_xor(mx, 16));
    mx = fmaxf(mx, __shfl_xor(mx, 32));
    float sum = 0.f;
    #pragma unroll
    for (int i = 0; i < 16; ++i) { ps[i] = __expf(ps[i] - mx); sum += ps[i]; }
    sum += __shfl_xor(sum, 16);
    sum += __shfl_xor(sum, 32);
    float inv = 1.f / sum;
    int j = w * 16 + l16;
    #pragma unroll
    for (int it = 0; it < 4; ++it) {
      bf16x4 pk;
      #pragma unroll
      for (int r = 0; r < 4; ++r) pk[r] = (bf16_t)(ps[it * 4 + r] * inv);
      *(bf16x4*)&sm.u.p2.aT[j * ND + ((it * 16 + q4 * 4) ^ ((j & 7) << 3))] = pk;
    }
  }
  __syncthreads();

  // ---- att[s][j] = sum_i v[s,i] a[i,j] -> attT[j][s] ----
  {
    const int sb = w * 32;
    f32x4 acc[2][4] = {};
    #pragma unroll
    for (int ki = 0; ki < 2; ++ki) {
      const int kb = ki * 32 + q4 * 8;
      bf16x8 afr[2];
      #pragma unroll
      for (int mt = 0; mt < 2; ++mt) {
        int srow = sb + mt * 16 + l16;
        afr[mt] = *(const bf16x8*)&sm.vS[srow * ND + (kb ^ ((srow & 7) << 3))];
      }
      #pragma unroll
      for (int nt = 0; nt < 4; ++nt) {
        int jrow = nt * 16 + l16;
        bf16x8 bfr = *(const bf16x8*)&sm.u.p2.aT[jrow * ND + (kb ^ ((jrow & 7) << 3))];
        #pragma unroll
        for (int mt = 0; mt < 2; ++mt)
          acc[mt][nt] = MFMA16(afr[mt], bfr, acc[mt][nt], 0, 0, 0);
      }
    }
    #pragma unroll
    for (int nt = 0; nt < 4; ++nt) {
      int j = nt * 16 + l16;
      #pragma unroll
      for (int mt = 0; mt < 2; ++mt) {
        bf16x4 pk;
        #pragma unroll
        for (int r = 0; r < 4; ++r) pk[r] = (bf16_t)acc[mt][nt][r];
        *(bf16x4*)&sm.u.p2.attT[j * NS + swz(j, sb + mt * 16 + q4 * 4)] = pk;
      }
    }
  }
  __syncthreads();

  // ---- dump attT -> att[b][d][hw][s] (linear 16B runs) ----
  #pragma unroll
  for (int jj = 0; jj < 4; ++jj) {
    int f = jj * 2048 + t * 8;
    int d = f >> 7, s0 = f & 127;
    bf16x8 v8 = *(const bf16x8*)&sm.u.p2.attT[d * NS + (s0 ^ ((d & 7) << 3))];
    *(bf16x8*)(att + ((size_t)((b * ND + d) * NHW + hw)) * NS + s0) = v8;
  }
}

// ================= Kernel C: out projection + residual =================
// grid 1024 = 8(ht of 32hw) * 8(dc of 8d) * 2(ch of 128c) * 8(b)
__global__ __launch_bounds__(256, 2) void out_proj(
    const bf16_t* __restrict__ att_ws,
    const bf16_t* __restrict__ woF, const float* __restrict__ bo,
    const float* __restrict__ x, float* __restrict__ out) {
  __shared__ bf16_t slab[256 * 128];  // [row=d8*hw32][s128], slot16-XOR by hw&7
  const int bid = blockIdx.x;
  const int ht = bid & 7, dc = (bid >> 3) & 7, ch = (bid >> 6) & 1, b = bid >> 7;
  const int t = threadIdx.x, w = t >> 6, lane = t & 63;
  const int l16 = lane & 15, g = lane >> 4;
  const int mh = w >> 1, nh = w & 1;

  {
    const int d = t >> 5, hw = t & 31;
    const bf16_t* src = att_ws + ((size_t)((b * ND + dc * 8 + d) * NHW + ht * 32 + hw)) * NS;
    const int row = d * 32 + hw;
    #pragma unroll
    for (int j = 0; j < 16; ++j) {
      bf16x8 v8 = *(const bf16x8*)(src + j * 8);
      *(bf16x8*)&slab[row * NS + ((j ^ (hw & 7)) << 3)] = v8;
    }
  }
  __syncthreads();

  f32x4 acc[4][8] = {};
  #pragma unroll
  for (int kq = 0; kq < 4; ++kq) {
    bf16x8 af[4];
    #pragma unroll
    for (int mt = 0; mt < 4; ++mt) {
      int c = ch * 128 + mh * 64 + mt * 16 + l16;
      af[mt] = *(const bf16x8*)(woF + (kq * 4 + g) * 2048 + c * 8);
    }
    #pragma unroll
    for (int nt = 0; nt < 8; ++nt) {
      int dl = nh * 4 + (nt >> 1);
      int hwl = (nt & 1) * 16 + l16;
      int row = dl * 32 + hwl;
      bf16x8 bfr = *(const bf16x8*)&slab[row * NS + (((kq * 4 + g) ^ (hwl & 7)) << 3)];
      #pragma unroll
      for (int mt = 0; mt < 4; ++mt)
        acc[mt][nt] = MFMA16(af[mt], bfr, acc[mt][nt], 0, 0, 0);
    }
  }

  #pragma unroll
  for (int mt = 0; mt < 4; ++mt) {
    #pragma unroll
    for (int r = 0; r < 4; ++r) {
      int c = ch * 128 + mh * 64 + mt * 16 + g * 4 + r;
      float bias = bo[c];
      #pragma unroll
      for (int nt = 0; nt < 8; ++nt) {
        int dg = dc * 8 + nh * 4 + (nt >> 1);
        int hwg = ht * 32 + (nt & 1) * 16 + l16;
        size_t gi = ((size_t)(b * NC + c) * ND + dg) * NHW + hwg;
        out[gi] = acc[mt][nt][r] + bias + x[gi];
      }
    }
  }
}

// ================= Fallback: round-1 fused kernel =================
struct SMemF {
  union {
    bf16_t xT[ND * NC];
    struct { bf16_t aT[ND * ND]; bf16_t attT[ND * NS]; } p2;
  } u;
  bf16_t kT[ND * NS];
  bf16_t qT[ND * NS];
  bf16_t vS[NS * ND];
};

__global__ __launch_bounds__(256) void attn_fused(
    const float* __restrict__ x,
    const float* __restrict__ wk, const float* __restrict__ bk,
    const float* __restrict__ wq, const float* __restrict__ bq,
    const float* __restrict__ wv, const float* __restrict__ bv,
    const float* __restrict__ wo, const float* __restrict__ bo,
    float* __restrict__ out) {
  __shared__ SMemF sm;
  const int gid = blockIdx.x;
  const int b = gid & 7;
  const int hw = gid >> 3;
  const int t = threadIdx.x;
  const int w = t >> 6;
  const int lane = t & 63;
  const int l16 = lane & 15;
  const int q4 = lane >> 4;
  const float* xb = x + (size_t)b * NC * ND * NHW + hw;
  {
    const int d = t & 63;
    const int cb = (t >> 6) * 64;
    for (int jj = 0; jj < 8; ++jj) {
      bf16x8 pk;
      #pragma unroll
      for (int e = 0; e < 8; ++e) {
        int c = cb + jj * 8 + e;
        pk[e] = (bf16_t)xb[(size_t)(c * ND + d) * NHW];
      }
      *(bf16x8*)&sm.u.xT[d * NC + swz(d, cb + jj * 8)] = pk;
    }
  }
  __syncthreads();
  {
    const int mat = w >> 1;
    const int sb = (w & 1) * 64;
    const float* wm = mat ? wq : wk;
    const float* bm = mat ? bq : bk;
    bf16_t* dst = mat ? sm.qT : sm.kT;
    f32x4 acc[4][4] = {};
    for (int ks = 0; ks < 8; ++ks) {
      const int kb = ks * 32 + q4 * 8;
      bf16x8 afr[4];
      #pragma unroll
      for (int mt = 0; mt < 4; ++mt) {
        int row = mt * 16 + l16;
        afr[mt] = *(const bf16x8*)&sm.u.xT[row * NC + swz(row, kb)];
      }
      #pragma unroll
      for (int st = 0; st < 4; ++st) {
        int s = sb + st * 16 + l16;
        bf16x8 bfr = ldg_w8(wm + s * NC + kb);
        #pragma unroll
        for (int mt = 0; mt < 4; ++mt)
          acc[mt][st] = MFMA16(afr[mt], bfr, acc[mt][st], 0, 0, 0);
      }
    }
    #pragma unroll
    for (int st = 0; st < 4; ++st) {
      int s = sb + st * 16 + l16;
      float bias = bm[s];
      #pragma unroll
      for (int mt = 0; mt < 4; ++mt) {
        #pragma unroll
        for (int r = 0; r < 4; ++r) {
          int d = mt * 16 + q4 * 4 + r;
          dst[d * NS + swz(d, s)] = (bf16_t)(acc[mt][st][r] + bias);
        }
      }
    }
  }
  {
    const int sb = w * 32;
    f32x4 acc[2][4] = {};
    for (int ks = 0; ks < 8; ++ks) {
      const int kb = ks * 32 + q4 * 8;
      bf16x8 afr[2];
      #pragma unroll
      for (int mt = 0; mt < 2; ++mt)
        afr[mt] = ldg_w8(wv + (sb + mt * 16 + l16) * NC + kb);
      #pragma unroll
      for (int nt = 0; nt < 4; ++nt) {
        int row = nt * 16 + l16;
        bf16x8 bfr = *(const bf16x8*)&sm.u.xT[row * NC + swz(row, kb)];
        #pragma unroll
        for (int mt = 0; mt < 2; ++mt)
          acc[mt][nt] = MFMA16(afr[mt], bfr, acc[mt][nt], 0, 0, 0);
      }
    }
    #pragma unroll
    for (int mt = 0; mt < 2; ++mt) {
      #pragma unroll
      for (int r = 0; r < 4; ++r) {
        int s = sb + mt * 16 + q4 * 4 + r;
        float bias = bv[s];
        #pragma unroll
        for (int nt = 0; nt < 4; ++nt) {
          int d = nt * 16 + l16;
          sm.vS[s * ND + swz(s, d)] = (bf16_t)(acc[mt][nt][r] + bias);
        }
      }
    }
  }
  __syncthreads();
  {
    f32x4 sacc[4] = {};
    for (int ks = 0; ks < 4; ++ks) {
      const int kb = ks * 32 + q4 * 8;
      int jrow = w * 16 + l16;
      bf16x8 bfr = *(const bf16x8*)&sm.qT[jrow * NS + swz(jrow, kb)];
      #pragma unroll
      for (int it = 0; it < 4; ++it) {
        int irow = it * 16 + l16;
        bf16x8 afr = *(const bf16x8*)&sm.kT[irow * NS + swz(irow, kb)];
        sacc[it] = MFMA16(afr, bfr, sacc[it], 0, 0, 0);
      }
    }
    const float scale = 0.088388347648318447f;
    float ps[16];
    float mx = -1e30f;
    #pragma unroll
    for (int it = 0; it < 4; ++it) {
      #pragma unroll
      for (int r = 0; r < 4; ++r) {
        float vv = sacc[it][r] * scale;
        ps[it * 4 + r] = vv;
        mx = fmaxf(mx, vv);
      }
    }
    mx = fmaxf(mx, __shfl_xor(mx, 16));
    mx = fmaxf(mx, __shfl_xor(mx, 32));
    float sum = 0.f;
    #pragma unroll
    for (int i = 0; i < 16; ++i) { ps[i] = __expf(ps[i] - mx); sum += ps[i]; }
    sum += __shfl_xor(sum, 16);
    sum += __shfl_xor(sum, 32);
    float inv = 1.f / sum;
    int j = w * 16 + l16;
    #pragma unroll
    for (int it = 0; it < 4; ++it) {
      bf16x4 pk;
      #pragma unroll
      for (int r = 0; r < 4; ++r) pk[r] = (bf16_t)(ps[it * 4 + r] * inv);
      *(bf16x4*)&sm.u.p2.aT[j * ND + swz(j, it * 16 + q4 * 4)] = pk;
    }
  }
  __syncthreads();
  {
    const int sb = w * 32;
    f32x4 acc[2][4] = {};
    #pragma unroll
    for (int ki = 0; ki < 2; ++ki) {
      const int kb = ki * 32 + q4 * 8;
      bf16x8 afr[2];
      #pragma unroll
      for (int mt = 0; mt < 2; ++mt) {
        int srow = sb + mt * 16 + l16;
        afr[mt] = *(const bf16x8*)&sm.vS[srow * ND + swz(srow, kb)];
      }
      #pragma unroll
      for (int nt = 0; nt < 4; ++nt) {
        int jrow = nt * 16 + l16;
        bf16x8 bfr = *(const bf16x8*)&sm.u.p2.aT[jrow * ND + swz(jrow, kb)];
        #pragma unroll
        for (int mt = 0; mt < 2; ++mt)
          acc[mt][nt] = MFMA16(afr[mt], bfr, acc[mt][nt], 0, 0, 0);
      }
    }
    #pragma unroll
    for (int nt = 0; nt < 4; ++nt) {
      int j = nt * 16 + l16;
      #pragma unroll
      for (int mt = 0; mt < 2; ++mt) {
        bf16x4 pk;
        #pragma unroll
        for (int r = 0; r < 4; ++r) pk[r] = (bf16_t)acc[mt][nt][r];
        *(bf16x4*)&sm.u.p2.attT[j * NS + swz(j, sb + mt * 16 + q4 * 4)] = pk;
      }
    }
  }
  __syncthreads();
  {
    const int cb = w * 64;
    f32x4 acc[4][4] = {};
    for (int ks = 0; ks < 4; ++ks) {
      const int kb = ks * 32 + q4 * 8;
      bf16x8 afr[4];
      #pragma unroll
      for (int mt = 0; mt < 4; ++mt)
        afr[mt] = ldg_w8(wo + (cb + mt * 16 + l16) * NS + kb);
      #pragma unroll
      for (int nt = 0; nt < 4; ++nt) {
        int jrow = nt * 16 + l16;
        bf16x8 bfr = *(const bf16x8*)&sm.u.p2.attT[jrow * NS + swz(jrow, kb)];
        #pragma unroll
        for (int mt = 0; mt < 4; ++mt)
          acc[mt][nt] = MFMA16(afr[mt], bfr, acc[mt][nt], 0, 0, 0);
      }
    }
    #pragma unroll
    for (int mt = 0; mt < 4; ++mt) {
      #pragma unroll
      for (int r = 0; r < 4; ++r) {
        int c = cb + mt * 16 + q4 * 4 + r;
        float bias = bo[c];
        #pragma unroll
        for (int nt = 0; nt < 4; ++nt) {
          int d = nt * 16 + l16;
          size_t gi = (size_t)(((b * NC + c) * ND + d) * NHW + hw);
          out[gi] = acc[mt][nt][r] + bias + x[gi];
        }
      }
    }
  }
}

extern "C" void kernel_launch(void* const* d_in, const int* in_sizes, int n_in,
                              void* d_out, int out_size, void* d_ws, size_t ws_size,
                              hipStream_t stream) {
  const float* x  = (const float*)d_in[0];
  const float* wk = (const float*)d_in[1];
  const float* bk = (const float*)d_in[2];
  const float* wq = (const float*)d_in[3];
  const float* bq = (const float*)d_in[4];
  const float* wv = (const float*)d_in[5];
  const float* bv = (const float*)d_in[6];
  const float* wo = (const float*)d_in[7];
  const float* bo = (const float*)d_in[8];
  float* out = (float*)d_out;

  // ws: [weights bf16 131072 el | xT 33554432 el | att 16777216 el]
  const size_t need = (size_t)(131072 + 33554432 + 16777216) * 2;
  if (ws_size >= need) {
    bf16_t* wsW = (bf16_t*)d_ws;
    bf16_t* xT  = wsW + 131072;
    bf16_t* att = xT + 33554432;
    transpose_x_w<<<dim3(8224), dim3(256), 0, stream>>>(x, wk, wq, wv, wo, xT, wsW);
    qkv_attn2<<<dim3(2048), dim3(256), 0, stream>>>(xT, wsW, bk, bq, bv, att);
    out_proj<<<dim3(1024), dim3(256), 0, stream>>>(att, wsW + 98304, bo, x, out);
  } else {
    attn_fused<<<dim3(2048), dim3(256), 0, stream>>>(x, wk, bk, wq, bq, wv, bv, wo, bo, out);
  }
}

// Round 5
// 139.812 us; speedup vs baseline: 3.3413x; 1.1456x over previous
//
#include <hip/hip_runtime.h>
#include <hip/hip_bf16.h>

// 3-kernel pipeline:
//   T: x [b][c][d][hw] fp32 -> xT [b][d][hw][c] bf16; weights -> fragmented bf16
//      wF layout: [c>>3][s][c&7] so MFMA fragments are 256B-coalesced runs.
//   F: fused QKV + per-(b,hw) attention, one block per (b,hw), grid 2048,
//      LDS 80KB -> 2 blocks/CU (2 waves/SIMD). att -> [b][d][hw][s] bf16.
//   C: out-projection + bias + residual -> out [b][c][d][hw] fp32
//      (epilogue staged through fp32 LDS for coalesced float4 I/O)
// Fallback: round-1 fused kernel if workspace too small.

typedef __bf16 bf16_t;
typedef bf16_t bf16x8 __attribute__((ext_vector_type(8)));
typedef bf16_t bf16x4 __attribute__((ext_vector_type(4)));
typedef float  f32x4  __attribute__((ext_vector_type(4)));

#define NB   8
#define NC   256
#define ND   64
#define NHW  256
#define NS   128

#define MFMA16 __builtin_amdgcn_mfma_f32_16x16x32_bf16

__device__ __forceinline__ int swz(int row, int col) {
  return col ^ ((row & 7) << 3);
}

__device__ __forceinline__ bf16x8 pack8(float4 a, float4 b) {
  bf16x8 r;
  r[0] = (bf16_t)a.x; r[1] = (bf16_t)a.y; r[2] = (bf16_t)a.z; r[3] = (bf16_t)a.w;
  r[4] = (bf16_t)b.x; r[5] = (bf16_t)b.y; r[6] = (bf16_t)b.z; r[7] = (bf16_t)b.w;
  return r;
}

__device__ __forceinline__ bf16x8 ldg_w8(const float* p) {
  float4 a = *(const float4*)p;
  float4 b = *(const float4*)(p + 4);
  return pack8(a, b);
}

// ================= Kernel T: transpose x -> xT bf16; fragment weights ========
// grid 8224: [0,8192): 64c x 64hw tile per (b,d); [8192,8224): weights
__global__ __launch_bounds__(256) void transpose_x_w(
    const float* __restrict__ x,
    const float* __restrict__ wk, const float* __restrict__ wq,
    const float* __restrict__ wv, const float* __restrict__ wo,
    bf16_t* __restrict__ xT, bf16_t* __restrict__ wsW) {
  __shared__ bf16_t tile[64 * 72];   // [hw][c] pad to 72
  const int bid = blockIdx.x;
  if (bid >= 8192) {
    const int wid = bid - 8192;
    const int mat = wid >> 3, sub = wid & 7;
    const int t = threadIdx.x;
    if (mat < 3) {
      // wk/wq/wv [128 s][256 c] -> frag [32 cg][128 s][8]
      const float* src = (mat == 0) ? wk : (mat == 1) ? wq : wv;
      bf16_t* dst = wsW + mat * 32768;
      int s = sub * 16 + (t >> 4), c0 = (t & 15) * 16;
      const float* p = src + s * NC + c0;
      float4 a0 = *(const float4*)p, a1 = *(const float4*)(p + 4);
      float4 a2 = *(const float4*)(p + 8), a3 = *(const float4*)(p + 12);
      *(bf16x8*)(dst + (c0 >> 3) * 1024 + s * 8)       = pack8(a0, a1);
      *(bf16x8*)(dst + ((c0 >> 3) + 1) * 1024 + s * 8) = pack8(a2, a3);
    } else {
      // wo [256 c][128 s] -> frag [16 sg][256 c][8]
      bf16_t* dst = wsW + 98304;
      int c = sub * 32 + (t >> 3), sc0 = (t & 7) * 16;
      const float* p = wo + c * NS + sc0;
      float4 a0 = *(const float4*)p, a1 = *(const float4*)(p + 4);
      float4 a2 = *(const float4*)(p + 8), a3 = *(const float4*)(p + 12);
      *(bf16x8*)(dst + (sc0 >> 3) * 2048 + c * 8)       = pack8(a0, a1);
      *(bf16x8*)(dst + ((sc0 >> 3) + 1) * 2048 + c * 8) = pack8(a2, a3);
    }
    return;
  }
  const int ct = bid & 3, hwt = (bid >> 2) & 3;
  const int d = (bid >> 4) & 63, b = bid >> 10;
  const int c0 = ct * 64, hw0 = hwt * 64;
  const int t = threadIdx.x;
  const int hwq = t & 15, chi = t >> 4;

  #pragma unroll
  for (int q = 0; q < 4; ++q) {
    int c = q * 16 + chi;
    float4 v4 = *(const float4*)(x + ((size_t)((b * NC + c0 + c) * ND + d)) * NHW + hw0 + hwq * 4);
    tile[(hwq * 4 + 0) * 72 + c] = (bf16_t)v4.x;
    tile[(hwq * 4 + 1) * 72 + c] = (bf16_t)v4.y;
    tile[(hwq * 4 + 2) * 72 + c] = (bf16_t)v4.z;
    tile[(hwq * 4 + 3) * 72 + c] = (bf16_t)v4.w;
  }
  __syncthreads();
  #pragma unroll
  for (int i = 0; i < 2; ++i) {
    int idx = t + 256 * i;
    int hw = idx >> 3, q = idx & 7;
    bf16x8 v8 = *(const bf16x8*)&tile[hw * 72 + q * 8];
    *(bf16x8*)(xT + ((size_t)((b * ND + d) * NHW + hw0 + hw)) * NC + c0 + q * 8) = v8;
  }
}

// ================= Kernel F: fused QKV + attention =================
// grid 2048 = (hw,b); 256 threads (4 waves); LDS 80KB -> 2 blocks/CU.
__global__ __launch_bounds__(256, 2) void qkv_attn2(
    const bf16_t* __restrict__ xT, const bf16_t* __restrict__ wsW,
    const float* __restrict__ bk, const float* __restrict__ bq,
    const float* __restrict__ bv, bf16_t* __restrict__ att) {
  __shared__ struct {
    union {
      bf16_t xTl[ND * NC];                       // 32KB [d][c] swz
      struct {
        bf16_t aT[ND * ND];                      // 8KB [j][i] swz
        bf16_t attT[ND * NS];                    // 16KB [d][s] swz
      } p2;
    } u;
    bf16_t kT[ND * NS];                          // 16KB [d][s] swz
    bf16_t qT[ND * NS];                          // 16KB
    bf16_t vS[NS * ND];                          // 16KB [s][d] swz
  } sm;
  const int gid = blockIdx.x;
  const int b = gid & 7, hw = gid >> 3;
  const int t = threadIdx.x, w = t >> 6, lane = t & 63;
  const int l16 = lane & 15, q4 = lane >> 4;

  const bf16_t* wkF = wsW;
  const bf16_t* wqF = wsW + 32768;
  const bf16_t* wvF = wsW + 65536;

  // ---- stage xT[b][*][hw][*] -> xTl[d][c] (coalesced 512B rows) ----
  #pragma unroll
  for (int jj = 0; jj < 8; ++jj) {
    int id = jj * 256 + t;
    int d = id >> 5, cg = (id & 31) * 8;
    bf16x8 v8 = *(const bf16x8*)(xT + ((size_t)((b * ND + d) * NHW + hw)) * NC + cg);
    *(bf16x8*)&sm.u.xTl[d * NC + swz(d, cg)] = v8;
  }
  __syncthreads();

  // ---- K,Q: waves 0,1 -> K (s-halves); waves 2,3 -> Q ----
  {
    const int mat = w >> 1;
    const int sb = (w & 1) * 64;
    const bf16_t* wm = mat ? wqF : wkF;
    const float* bm = mat ? bq : bk;
    bf16_t* dst = mat ? sm.qT : sm.kT;
    f32x4 acc[4][4] = {};
    for (int ks = 0; ks < 8; ++ks) {
      const int kb = ks * 32 + q4 * 8;
      bf16x8 afr[4];
      #pragma unroll
      for (int mt = 0; mt < 4; ++mt) {
        int s = sb + mt * 16 + l16;
        afr[mt] = *(const bf16x8*)(wm + (kb >> 3) * 1024 + s * 8);
      }
      #pragma unroll
      for (int nt = 0; nt < 4; ++nt) {
        int row = nt * 16 + l16;
        bf16x8 bfr = *(const bf16x8*)&sm.u.xTl[row * NC + swz(row, kb)];
        #pragma unroll
        for (int mt = 0; mt < 4; ++mt)
          acc[mt][nt] = MFMA16(afr[mt], bfr, acc[mt][nt], 0, 0, 0);
      }
    }
    #pragma unroll
    for (int mt = 0; mt < 4; ++mt) {
      int s0 = sb + mt * 16 + q4 * 4;
      float4 b4 = *(const float4*)(bm + s0);
      #pragma unroll
      for (int nt = 0; nt < 4; ++nt) {
        int d = nt * 16 + l16;
        bf16x4 pk;
        pk[0] = (bf16_t)(acc[mt][nt][0] + b4.x);
        pk[1] = (bf16_t)(acc[mt][nt][1] + b4.y);
        pk[2] = (bf16_t)(acc[mt][nt][2] + b4.z);
        pk[3] = (bf16_t)(acc[mt][nt][3] + b4.w);
        *(bf16x4*)&dst[d * NS + swz(d, s0)] = pk;
      }
    }
  }

  // ---- V: A = xTl (m=d), B = Wv rows (n=s, frag). C: row=d, col=s ----
  {
    const int sb = w * 32;
    f32x4 acc[4][2] = {};
    for (int ks = 0; ks < 8; ++ks) {
      const int kb = ks * 32 + q4 * 8;
      bf16x8 afr[4], bfr[2];
      #pragma unroll
      for (int mt = 0; mt < 4; ++mt) {
        int row = mt * 16 + l16;
        afr[mt] = *(const bf16x8*)&sm.u.xTl[row * NC + swz(row, kb)];
      }
      #pragma unroll
      for (int nt = 0; nt < 2; ++nt) {
        int s = sb + nt * 16 + l16;
        bfr[nt] = *(const bf16x8*)(wvF + (kb >> 3) * 1024 + s * 8);
      }
      #pragma unroll
      for (int nt = 0; nt < 2; ++nt)
        #pragma unroll
        for (int mt = 0; mt < 4; ++mt)
          acc[mt][nt] = MFMA16(afr[mt], bfr[nt], acc[mt][nt], 0, 0, 0);
    }
    #pragma unroll
    for (int nt = 0; nt < 2; ++nt) {
      int s = sb + nt * 16 + l16;
      float bvs = bv[s];
      #pragma unroll
      for (int mt = 0; mt < 4; ++mt) {
        int d0 = mt * 16 + q4 * 4;
        bf16x4 pv;
        pv[0] = (bf16_t)(acc[mt][nt][0] + bvs);
        pv[1] = (bf16_t)(acc[mt][nt][1] + bvs);
        pv[2] = (bf16_t)(acc[mt][nt][2] + bvs);
        pv[3] = (bf16_t)(acc[mt][nt][3] + bvs);
        *(bf16x4*)&sm.vS[s * ND + (d0 ^ ((s & 7) << 3))] = pv;
      }
    }
  }
  __syncthreads();

  // ---- scores[i][j] = sum_s kT[i][s] qT[j][s]; softmax over i -> aT[j][i] ----
  {
    f32x4 sacc[4] = {};
    for (int ks = 0; ks < 4; ++ks) {
      const int kb = ks * 32 + q4 * 8;
      int jrow = w * 16 + l16;
      bf16x8 bfr = *(const bf16x8*)&sm.qT[jrow * NS + swz(jrow, kb)];
      #pragma unroll
      for (int it = 0; it < 4; ++it) {
        int irow = it * 16 + l16;
        bf16x8 afr = *(const bf16x8*)&sm.kT[irow * NS + swz(irow, kb)];
        sacc[it] = MFMA16(afr, bfr, sacc[it], 0, 0, 0);
      }
    }
    const float scale = 0.088388347648318447f;  // 1/sqrt(128)
    float ps[16];
    float mx = -1e30f;
    #pragma unroll
    for (int it = 0; it < 4; ++it)
      #pragma unroll
      for (int r = 0; r < 4; ++r) {
        float vv = sacc[it][r] * scale;
        ps[it * 4 + r] = vv;
        mx = fmaxf(mx, vv);
      }
    mx = fmaxf(mx, __shfl_xor(mx, 16));
    mx = fmaxf(mx, __shfl_xor(mx, 32));
    float sum = 0.f;
    #pragma unroll
    for (int i = 0; i < 16; ++i) { ps[i] = __expf(ps[i] - mx); sum += ps[i]; }
    sum += __shfl_xor(sum, 16);
    sum += __shfl_xor(sum, 32);
    float inv = 1.f / sum;
    int j = w * 16 + l16;
    #pragma unroll
    for (int it = 0; it < 4; ++it) {
      bf16x4 pk;
      #pragma unroll
      for (int r = 0; r < 4; ++r) pk[r] = (bf16_t)(ps[it * 4 + r] * inv);
      *(bf16x4*)&sm.u.p2.aT[j * ND + ((it * 16 + q4 * 4) ^ ((j & 7) << 3))] = pk;
    }
  }
  __syncthreads();

  // ---- att[s][j] = sum_i v[s,i] a[i,j] -> attT[j][s] ----
  {
    const int sb = w * 32;
    f32x4 acc[2][4] = {};
    #pragma unroll
    for (int ki = 0; ki < 2; ++ki) {
      const int kb = ki * 32 + q4 * 8;
      bf16x8 afr[2];
      #pragma unroll
      for (int mt = 0; mt < 2; ++mt) {
        int srow = sb + mt * 16 + l16;
        afr[mt] = *(const bf16x8*)&sm.vS[srow * ND + (kb ^ ((srow & 7) << 3))];
      }
      #pragma unroll
      for (int nt = 0; nt < 4; ++nt) {
        int jrow = nt * 16 + l16;
        bf16x8 bfr = *(const bf16x8*)&sm.u.p2.aT[jrow * ND + (kb ^ ((jrow & 7) << 3))];
        #pragma unroll
        for (int mt = 0; mt < 2; ++mt)
          acc[mt][nt] = MFMA16(afr[mt], bfr, acc[mt][nt], 0, 0, 0);
      }
    }
    #pragma unroll
    for (int nt = 0; nt < 4; ++nt) {
      int j = nt * 16 + l16;
      #pragma unroll
      for (int mt = 0; mt < 2; ++mt) {
        bf16x4 pk;
        #pragma unroll
        for (int r = 0; r < 4; ++r) pk[r] = (bf16_t)acc[mt][nt][r];
        *(bf16x4*)&sm.u.p2.attT[j * NS + swz(j, sb + mt * 16 + q4 * 4)] = pk;
      }
    }
  }
  __syncthreads();

  // ---- dump attT -> att[b][d][hw][s] (linear 16B runs) ----
  #pragma unroll
  for (int jj = 0; jj < 4; ++jj) {
    int f = jj * 2048 + t * 8;
    int d = f >> 7, s0 = f & 127;
    bf16x8 v8 = *(const bf16x8*)&sm.u.p2.attT[d * NS + (s0 ^ ((d & 7) << 3))];
    *(bf16x8*)(att + ((size_t)((b * ND + d) * NHW + hw)) * NS + s0) = v8;
  }
}

// ================= Kernel C: out projection + residual =================
// grid 1024 = 8(ht of 32hw) * 8(dc of 8d) * 2(ch of 128c) * 8(b)
// Epilogue: acc -> fp32 LDS stage (2 rounds of 64c) -> coalesced float4 I/O.
__global__ __launch_bounds__(256, 2) void out_proj(
    const bf16_t* __restrict__ att_ws,
    const bf16_t* __restrict__ woF, const float* __restrict__ bo,
    const float* __restrict__ x, float* __restrict__ out) {
  __shared__ union {
    bf16_t slab[256 * 128];   // [row=d8*hw32][s128], slot16-XOR by hw&7
    float  stage[64 * 256];   // [c&63][dl*32+hw], hw XOR'd by ((c>>2)&3)<<3
  } sm;
  const int bid = blockIdx.x;
  const int ht = bid & 7, dc = (bid >> 3) & 7, ch = (bid >> 6) & 1, b = bid >> 7;
  const int t = threadIdx.x, w = t >> 6, lane = t & 63;
  const int l16 = lane & 15, g = lane >> 4;
  const int mh = w >> 1, nh = w & 1;

  {
    const int d = t >> 5, hw = t & 31;
    const bf16_t* src = att_ws + ((size_t)((b * ND + dc * 8 + d) * NHW + ht * 32 + hw)) * NS;
    const int row = d * 32 + hw;
    #pragma unroll
    for (int j = 0; j < 16; ++j) {
      bf16x8 v8 = *(const bf16x8*)(src + j * 8);
      *(bf16x8*)&sm.slab[row * NS + ((j ^ (hw & 7)) << 3)] = v8;
    }
  }
  __syncthreads();

  f32x4 acc[4][8] = {};
  #pragma unroll
  for (int kq = 0; kq < 4; ++kq) {
    bf16x8 af[4];
    #pragma unroll
    for (int mt = 0; mt < 4; ++mt) {
      int c = ch * 128 + mh * 64 + mt * 16 + l16;
      af[mt] = *(const bf16x8*)(woF + (kq * 4 + g) * 2048 + c * 8);
    }
    #pragma unroll
    for (int nt = 0; nt < 8; ++nt) {
      int dl = nh * 4 + (nt >> 1);
      int hwl = (nt & 1) * 16 + l16;
      int row = dl * 32 + hwl;
      bf16x8 bfr = *(const bf16x8*)&sm.slab[row * NS + (((kq * 4 + g) ^ (hwl & 7)) << 3)];
      #pragma unroll
      for (int mt = 0; mt < 4; ++mt)
        acc[mt][nt] = MFMA16(af[mt], bfr, acc[mt][nt], 0, 0, 0);
    }
  }

  // ---- staged epilogue: two rounds of 64 c ----
  #pragma unroll
  for (int p = 0; p < 2; ++p) {
    __syncthreads();
    if (mh == p) {
      #pragma unroll
      for (int mt = 0; mt < 4; ++mt) {
        #pragma unroll
        for (int nt = 0; nt < 8; ++nt) {
          int dl = nh * 4 + (nt >> 1);
          int hws = ((nt & 1) * 16 + l16) ^ (g << 3);
          int base = (mt * 16 + g * 4) * 256 + dl * 32 + hws;
          #pragma unroll
          for (int r = 0; r < 4; ++r)
            sm.stage[base + r * 256] = acc[mt][nt][r];
        }
      }
    }
    __syncthreads();
    #pragma unroll
    for (int ii = 0; ii < 16; ++ii) {
      int c6 = ii * 4 + w;                       // wave-uniform
      int c = ch * 128 + p * 64 + c6;
      int dq = (lane >> 3) & 7;
      int hw4 = (lane & 7) * 4;
      float4 v = *(const float4*)&sm.stage[c6 * 256 + dq * 32 + (hw4 ^ ((ii & 3) << 3))];
      size_t gi = ((size_t)(b * NC + c) * ND + dc * 8 + dq) * NHW + ht * 32 + hw4;
      float4 xv = *(const float4*)(x + gi);
      float bias = bo[c];
      float4 o;
      o.x = v.x + bias + xv.x;
      o.y = v.y + bias + xv.y;
      o.z = v.z + bias + xv.z;
      o.w = v.w + bias + xv.w;
      *(float4*)(out + gi) = o;
    }
  }
}

// ================= Fallback: round-1 fused kernel =================
struct SMemF {
  union {
    bf16_t xT[ND * NC];
    struct { bf16_t aT[ND * ND]; bf16_t attT[ND * NS]; } p2;
  } u;
  bf16_t kT[ND * NS];
  bf16_t qT[ND * NS];
  bf16_t vS[NS * ND];
};

__global__ __launch_bounds__(256) void attn_fused(
    const float* __restrict__ x,
    const float* __restrict__ wk, const float* __restrict__ bk,
    const float* __restrict__ wq, const float* __restrict__ bq,
    const float* __restrict__ wv, const float* __restrict__ bv,
    const float* __restrict__ wo, const float* __restrict__ bo,
    float* __restrict__ out) {
  __shared__ SMemF sm;
  const int gid = blockIdx.x;
  const int b = gid & 7;
  const int hw = gid >> 3;
  const int t = threadIdx.x;
  const int w = t >> 6;
  const int lane = t & 63;
  const int l16 = lane & 15;
  const int q4 = lane >> 4;
  const float* xb = x + (size_t)b * NC * ND * NHW + hw;
  {
    const int d = t & 63;
    const int cb = (t >> 6) * 64;
    for (int jj = 0; jj < 8; ++jj) {
      bf16x8 pk;
      #pragma unroll
      for (int e = 0; e < 8; ++e) {
        int c = cb + jj * 8 + e;
        pk[e] = (bf16_t)xb[(size_t)(c * ND + d) * NHW];
      }
      *(bf16x8*)&sm.u.xT[d * NC + swz(d, cb + jj * 8)] = pk;
    }
  }
  __syncthreads();
  {
    const int mat = w >> 1;
    const int sb = (w & 1) * 64;
    const float* wm = mat ? wq : wk;
    const float* bm = mat ? bq : bk;
    bf16_t* dst = mat ? sm.qT : sm.kT;
    f32x4 acc[4][4] = {};
    for (int ks = 0; ks < 8; ++ks) {
      const int kb = ks * 32 + q4 * 8;
      bf16x8 afr[4];
      #pragma unroll
      for (int mt = 0; mt < 4; ++mt) {
        int row = mt * 16 + l16;
        afr[mt] = *(const bf16x8*)&sm.u.xT[row * NC + swz(row, kb)];
      }
      #pragma unroll
      for (int st = 0; st < 4; ++st) {
        int s = sb + st * 16 + l16;
        bf16x8 bfr = ldg_w8(wm + s * NC + kb);
        #pragma unroll
        for (int mt = 0; mt < 4; ++mt)
          acc[mt][st] = MFMA16(afr[mt], bfr, acc[mt][st], 0, 0, 0);
      }
    }
    #pragma unroll
    for (int st = 0; st < 4; ++st) {
      int s = sb + st * 16 + l16;
      float bias = bm[s];
      #pragma unroll
      for (int mt = 0; mt < 4; ++mt) {
        #pragma unroll
        for (int r = 0; r < 4; ++r) {
          int d = mt * 16 + q4 * 4 + r;
          dst[d * NS + swz(d, s)] = (bf16_t)(acc[mt][st][r] + bias);
        }
      }
    }
  }
  {
    const int sb = w * 32;
    f32x4 acc[2][4] = {};
    for (int ks = 0; ks < 8; ++ks) {
      const int kb = ks * 32 + q4 * 8;
      bf16x8 afr[2];
      #pragma unroll
      for (int mt = 0; mt < 2; ++mt)
        afr[mt] = ldg_w8(wv + (sb + mt * 16 + l16) * NC + kb);
      #pragma unroll
      for (int nt = 0; nt < 4; ++nt) {
        int row = nt * 16 + l16;
        bf16x8 bfr = *(const bf16x8*)&sm.u.xT[row * NC + swz(row, kb)];
        #pragma unroll
        for (int mt = 0; mt < 2; ++mt)
          acc[mt][nt] = MFMA16(afr[mt], bfr, acc[mt][nt], 0, 0, 0);
      }
    }
    #pragma unroll
    for (int mt = 0; mt < 2; ++mt) {
      #pragma unroll
      for (int r = 0; r < 4; ++r) {
        int s = sb + mt * 16 + q4 * 4 + r;
        float bias = bv[s];
        #pragma unroll
        for (int nt = 0; nt < 4; ++nt) {
          int d = nt * 16 + l16;
          sm.vS[s * ND + swz(s, d)] = (bf16_t)(acc[mt][nt][r] + bias);
        }
      }
    }
  }
  __syncthreads();
  {
    f32x4 sacc[4] = {};
    for (int ks = 0; ks < 4; ++ks) {
      const int kb = ks * 32 + q4 * 8;
      int jrow = w * 16 + l16;
      bf16x8 bfr = *(const bf16x8*)&sm.qT[jrow * NS + swz(jrow, kb)];
      #pragma unroll
      for (int it = 0; it < 4; ++it) {
        int irow = it * 16 + l16;
        bf16x8 afr = *(const bf16x8*)&sm.kT[irow * NS + swz(irow, kb)];
        sacc[it] = MFMA16(afr, bfr, sacc[it], 0, 0, 0);
      }
    }
    const float scale = 0.088388347648318447f;
    float ps[16];
    float mx = -1e30f;
    #pragma unroll
    for (int it = 0; it < 4; ++it) {
      #pragma unroll
      for (int r = 0; r < 4; ++r) {
        float vv = sacc[it][r] * scale;
        ps[it * 4 + r] = vv;
        mx = fmaxf(mx, vv);
      }
    }
    mx = fmaxf(mx, __shfl_xor(mx, 16));
    mx = fmaxf(mx, __shfl_xor(mx, 32));
    float sum = 0.f;
    #pragma unroll
    for (int i = 0; i < 16; ++i) { ps[i] = __expf(ps[i] - mx); sum += ps[i]; }
    sum += __shfl_xor(sum, 16);
    sum += __shfl_xor(sum, 32);
    float inv = 1.f / sum;
    int j = w * 16 + l16;
    #pragma unroll
    for (int it = 0; it < 4; ++it) {
      bf16x4 pk;
      #pragma unroll
      for (int r = 0; r < 4; ++r) pk[r] = (bf16_t)(ps[it * 4 + r] * inv);
      *(bf16x4*)&sm.u.p2.aT[j * ND + swz(j, it * 16 + q4 * 4)] = pk;
    }
  }
  __syncthreads();
  {
    const int sb = w * 32;
    f32x4 acc[2][4] = {};
    #pragma unroll
    for (int ki = 0; ki < 2; ++ki) {
      const int kb = ki * 32 + q4 * 8;
      bf16x8 afr[2];
      #pragma unroll
      for (int mt = 0; mt < 2; ++mt) {
        int srow = sb + mt * 16 + l16;
        afr[mt] = *(const bf16x8*)&sm.vS[srow * ND + swz(srow, kb)];
      }
      #pragma unroll
      for (int nt = 0; nt < 4; ++nt) {
        int jrow = nt * 16 + l16;
        bf16x8 bfr = *(const bf16x8*)&sm.u.p2.aT[jrow * ND + swz(jrow, kb)];
        #pragma unroll
        for (int mt = 0; mt < 2; ++mt)
          acc[mt][nt] = MFMA16(afr[mt], bfr, acc[mt][nt], 0, 0, 0);
      }
    }
    #pragma unroll
    for (int nt = 0; nt < 4; ++nt) {
      int j = nt * 16 + l16;
      #pragma unroll
      for (int mt = 0; mt < 2; ++mt) {
        bf16x4 pk;
        #pragma unroll
        for (int r = 0; r < 4; ++r) pk[r] = (bf16_t)acc[mt][nt][r];
        *(bf16x4*)&sm.u.p2.attT[j * NS + swz(j, sb + mt * 16 + q4 * 4)] = pk;
      }
    }
  }
  __syncthreads();
  {
    const int cb = w * 64;
    f32x4 acc[4][4] = {};
    for (int ks = 0; ks < 4; ++ks) {
      const int kb = ks * 32 + q4 * 8;
      bf16x8 afr[4];
      #pragma unroll
      for (int mt = 0; mt < 4; ++mt)
        afr[mt] = ldg_w8(wo + (cb + mt * 16 + l16) * NS + kb);
      #pragma unroll
      for (int nt = 0; nt < 4; ++nt) {
        int jrow = nt * 16 + l16;
        bf16x8 bfr = *(const bf16x8*)&sm.u.p2.attT[jrow * NS + swz(jrow, kb)];
        #pragma unroll
        for (int mt = 0; mt < 4; ++mt)
          acc[mt][nt] = MFMA16(afr[mt], bfr, acc[mt][nt], 0, 0, 0);
      }
    }
    #pragma unroll
    for (int mt = 0; mt < 4; ++mt) {
      #pragma unroll
      for (int r = 0; r < 4; ++r) {
        int c = cb + mt * 16 + q4 * 4 + r;
        float bias = bo[c];
        #pragma unroll
        for (int nt = 0; nt < 4; ++nt) {
          int d = nt * 16 + l16;
          size_t gi = (size_t)(((b * NC + c) * ND + d) * NHW + hw);
          out[gi] = acc[mt][nt][r] + bias + x[gi];
        }
      }
    }
  }
}

extern "C" void kernel_launch(void* const* d_in, const int* in_sizes, int n_in,
                              void* d_out, int out_size, void* d_ws, size_t ws_size,
                              hipStream_t stream) {
  const float* x  = (const float*)d_in[0];
  const float* wk = (const float*)d_in[1];
  const float* bk = (const float*)d_in[2];
  const float* wq = (const float*)d_in[3];
  const float* bq = (const float*)d_in[4];
  const float* wv = (const float*)d_in[5];
  const float* bv = (const float*)d_in[6];
  const float* wo = (const float*)d_in[7];
  const float* bo = (const float*)d_in[8];
  float* out = (float*)d_out;

  // ws: [weights bf16 131072 el | xT 33554432 el | att 16777216 el]
  const size_t need = (size_t)(131072 + 33554432 + 16777216) * 2;
  if (ws_size >= need) {
    bf16_t* wsW = (bf16_t*)d_ws;
    bf16_t* xT  = wsW + 131072;
    bf16_t* att = xT + 33554432;
    transpose_x_w<<<dim3(8224), dim3(256), 0, stream>>>(x, wk, wq, wv, wo, xT, wsW);
    qkv_attn2<<<dim3(2048), dim3(256), 0, stream>>>(xT, wsW, bk, bq, bv, att);
    out_proj<<<dim3(1024), dim3(256), 0, stream>>>(att, wsW + 98304, bo, x, out);
  } else {
    attn_fused<<<dim3(2048), dim3(256), 0, stream>>>(x, wk, bk, wq, bq, wv, bv, wo, bo, out);
  }
}

// Round 6
// 136.457 us; speedup vs baseline: 3.4234x; 1.0246x over previous
//
#include <hip/hip_runtime.h>
#include <hip/hip_bf16.h>

// 3-kernel pipeline:
//   T: x [b][c][d][hw] fp32 -> xT [b][d][hw][c] bf16; weights -> fragmented bf16
//      wF layout: [c>>3][s][c&7] so MFMA fragments are 256B-coalesced runs.
//   F: fused QKV + per-(b,hw) attention, one block per (b,hw), grid 2048.
//      48KB LDS (c-sliced xTl staging + region overlays) -> 3 blocks/CU;
//      V accumulation fused into the K/Q k-loop (shared xTl fragments).
//      att -> [b][d][hw][s] bf16.
//   C: out-projection + bias + residual -> out [b][c][d][hw] fp32
//      (epilogue staged through fp32 LDS for coalesced float4 I/O)
// Fallback: round-1 fused kernel if workspace too small.

typedef __bf16 bf16_t;
typedef bf16_t bf16x8 __attribute__((ext_vector_type(8)));
typedef bf16_t bf16x4 __attribute__((ext_vector_type(4)));
typedef float  f32x4  __attribute__((ext_vector_type(4)));

#define NB   8
#define NC   256
#define ND   64
#define NHW  256
#define NS   128

#define MFMA16 __builtin_amdgcn_mfma_f32_16x16x32_bf16

__device__ __forceinline__ int swz(int row, int col) {
  return col ^ ((row & 7) << 3);
}

__device__ __forceinline__ bf16x8 pack8(float4 a, float4 b) {
  bf16x8 r;
  r[0] = (bf16_t)a.x; r[1] = (bf16_t)a.y; r[2] = (bf16_t)a.z; r[3] = (bf16_t)a.w;
  r[4] = (bf16_t)b.x; r[5] = (bf16_t)b.y; r[6] = (bf16_t)b.z; r[7] = (bf16_t)b.w;
  return r;
}

__device__ __forceinline__ bf16x8 ldg_w8(const float* p) {
  float4 a = *(const float4*)p;
  float4 b = *(const float4*)(p + 4);
  return pack8(a, b);
}

// ================= Kernel T: transpose x -> xT bf16; fragment weights ========
// grid 8224: [0,8192): 64c x 64hw tile per (b,d); [8192,8224): weights
__global__ __launch_bounds__(256) void transpose_x_w(
    const float* __restrict__ x,
    const float* __restrict__ wk, const float* __restrict__ wq,
    const float* __restrict__ wv, const float* __restrict__ wo,
    bf16_t* __restrict__ xT, bf16_t* __restrict__ wsW) {
  __shared__ bf16_t tile[64 * 72];   // [hw][c] pad to 72
  const int bid = blockIdx.x;
  if (bid >= 8192) {
    const int wid = bid - 8192;
    const int mat = wid >> 3, sub = wid & 7;
    const int t = threadIdx.x;
    if (mat < 3) {
      // wk/wq/wv [128 s][256 c] -> frag [32 cg][128 s][8]
      const float* src = (mat == 0) ? wk : (mat == 1) ? wq : wv;
      bf16_t* dst = wsW + mat * 32768;
      int s = sub * 16 + (t >> 4), c0 = (t & 15) * 16;
      const float* p = src + s * NC + c0;
      float4 a0 = *(const float4*)p, a1 = *(const float4*)(p + 4);
      float4 a2 = *(const float4*)(p + 8), a3 = *(const float4*)(p + 12);
      *(bf16x8*)(dst + (c0 >> 3) * 1024 + s * 8)       = pack8(a0, a1);
      *(bf16x8*)(dst + ((c0 >> 3) + 1) * 1024 + s * 8) = pack8(a2, a3);
    } else {
      // wo [256 c][128 s] -> frag [16 sg][256 c][8]
      bf16_t* dst = wsW + 98304;
      int c = sub * 32 + (t >> 3), sc0 = (t & 7) * 16;
      const float* p = wo + c * NS + sc0;
      float4 a0 = *(const float4*)p, a1 = *(const float4*)(p + 4);
      float4 a2 = *(const float4*)(p + 8), a3 = *(const float4*)(p + 12);
      *(bf16x8*)(dst + (sc0 >> 3) * 2048 + c * 8)       = pack8(a0, a1);
      *(bf16x8*)(dst + ((sc0 >> 3) + 1) * 2048 + c * 8) = pack8(a2, a3);
    }
    return;
  }
  const int ct = bid & 3, hwt = (bid >> 2) & 3;
  const int d = (bid >> 4) & 63, b = bid >> 10;
  const int c0 = ct * 64, hw0 = hwt * 64;
  const int t = threadIdx.x;
  const int hwq = t & 15, chi = t >> 4;

  #pragma unroll
  for (int q = 0; q < 4; ++q) {
    int c = q * 16 + chi;
    float4 v4 = *(const float4*)(x + ((size_t)((b * NC + c0 + c) * ND + d)) * NHW + hw0 + hwq * 4);
    tile[(hwq * 4 + 0) * 72 + c] = (bf16_t)v4.x;
    tile[(hwq * 4 + 1) * 72 + c] = (bf16_t)v4.y;
    tile[(hwq * 4 + 2) * 72 + c] = (bf16_t)v4.z;
    tile[(hwq * 4 + 3) * 72 + c] = (bf16_t)v4.w;
  }
  __syncthreads();
  #pragma unroll
  for (int i = 0; i < 2; ++i) {
    int idx = t + 256 * i;
    int hw = idx >> 3, q = idx & 7;
    bf16x8 v8 = *(const bf16x8*)&tile[hw * 72 + q * 8];
    *(bf16x8*)(xT + ((size_t)((b * ND + d) * NHW + hw0 + hw)) * NC + c0 + q * 8) = v8;
  }
}

// ================= Kernel F: fused QKV + attention (48KB LDS) =================
// grid 2048 = (hw,b); 256 threads (4 waves); 3 blocks/CU.
// LDS overlays: [0,8192): kT / xTl-slice / aT ; [8192,16384): qT / attT ;
//               [16384,24576): vS.
__global__ __launch_bounds__(256, 3) void qkv_attn3(
    const bf16_t* __restrict__ xT, const bf16_t* __restrict__ wsW,
    const float* __restrict__ bk, const float* __restrict__ bq,
    const float* __restrict__ bv, bf16_t* __restrict__ att) {
  __shared__ bf16_t lds[24576];          // 48 KB
  bf16_t* kT   = lds;                    // [d][s] swz (8192 els)
  bf16_t* qT   = lds + 8192;             // [d][s] swz
  bf16_t* vS   = lds + 16384;            // [s][d] swz
  bf16_t* xTl  = lds;                    // [d][128c] swz (slice; dead pre-epilogue)
  bf16_t* aT   = lds;                    // [j][i] swz (4096 els; post-QK^T)
  bf16_t* attT = lds + 8192;             // [d][s] swz (post-QK^T)

  const int gid = blockIdx.x;
  const int b = gid & 7, hw = gid >> 3;
  const int t = threadIdx.x, w = t >> 6, lane = t & 63;
  const int l16 = lane & 15, q4 = lane >> 4;

  // K: waves 0,1 (s-halves); Q: waves 2,3. V: all waves, s = w*32..+32.
  const int mat = w >> 1;
  const int sb = (w & 1) * 64;
  const bf16_t* wm = mat ? (wsW + 32768) : wsW;    // wq : wk frag
  const bf16_t* wvF = wsW + 65536;
  const float* bm = mat ? bq : bk;
  bf16_t* dstKQ = mat ? qT : kT;
  const int sbv = w * 32;

  f32x4 acc[4][4] = {};     // K-or-Q accumulator (row=s, col=d)
  f32x4 accv[4][2] = {};    // V accumulator (row=d, col=s)

  for (int cc = 0; cc < 2; ++cc) {
    __syncthreads();
    // stage xT slice [64 d][128 c] (256B coalesced runs), swizzled dest
    #pragma unroll
    for (int jj = 0; jj < 4; ++jj) {
      int id = jj * 256 + t;
      int d = id >> 4, cg = (id & 15) * 8;
      bf16x8 v8 = *(const bf16x8*)(xT + ((size_t)((b * ND + d) * NHW + hw)) * NC + cc * 128 + cg);
      *(bf16x8*)&xTl[d * 128 + swz(d, cg)] = v8;
    }
    __syncthreads();
    #pragma unroll
    for (int ks = 0; ks < 4; ++ks) {
      const int kb = ks * 32 + q4 * 8;          // c within slice
      const int kgf = ((cc * 128 + kb) >> 3) * 1024;  // weight frag row offset
      bf16x8 xfr[4], afk[4], bfv[2];
      #pragma unroll
      for (int i = 0; i < 4; ++i) {
        int row = i * 16 + l16;                 // d rows (B for K/Q, A for V)
        xfr[i] = *(const bf16x8*)&xTl[row * 128 + swz(row, kb)];
        int s = sb + i * 16 + l16;              // A rows (s) for K/Q
        afk[i] = *(const bf16x8*)(wm + kgf + s * 8);
      }
      #pragma unroll
      for (int i = 0; i < 2; ++i) {
        int s = sbv + i * 16 + l16;             // B rows (s) for V
        bfv[i] = *(const bf16x8*)(wvF + kgf + s * 8);
      }
      #pragma unroll
      for (int nt = 0; nt < 4; ++nt)
        #pragma unroll
        for (int mt = 0; mt < 4; ++mt)
          acc[mt][nt] = MFMA16(afk[mt], xfr[nt], acc[mt][nt], 0, 0, 0);
      #pragma unroll
      for (int nt = 0; nt < 2; ++nt)
        #pragma unroll
        for (int mt = 0; mt < 4; ++mt)
          accv[mt][nt] = MFMA16(xfr[mt], bfv[nt], accv[mt][nt], 0, 0, 0);
    }
  }
  __syncthreads();   // xTl dead; epilogue overwrites its region (kT)

  // ---- epilogue: K/Q -> kT/qT [d][s]; V -> vS [s][d] ----
  #pragma unroll
  for (int mt = 0; mt < 4; ++mt) {
    int s0 = sb + mt * 16 + q4 * 4;
    float4 b4 = *(const float4*)(bm + s0);
    #pragma unroll
    for (int nt = 0; nt < 4; ++nt) {
      int d = nt * 16 + l16;
      bf16x4 pk;
      pk[0] = (bf16_t)(acc[mt][nt][0] + b4.x);
      pk[1] = (bf16_t)(acc[mt][nt][1] + b4.y);
      pk[2] = (bf16_t)(acc[mt][nt][2] + b4.z);
      pk[3] = (bf16_t)(acc[mt][nt][3] + b4.w);
      *(bf16x4*)&dstKQ[d * NS + swz(d, s0)] = pk;
    }
  }
  #pragma unroll
  for (int nt = 0; nt < 2; ++nt) {
    int s = sbv + nt * 16 + l16;
    float bvs = bv[s];
    #pragma unroll
    for (int mt = 0; mt < 4; ++mt) {
      int d0 = mt * 16 + q4 * 4;
      bf16x4 pv;
      pv[0] = (bf16_t)(accv[mt][nt][0] + bvs);
      pv[1] = (bf16_t)(accv[mt][nt][1] + bvs);
      pv[2] = (bf16_t)(accv[mt][nt][2] + bvs);
      pv[3] = (bf16_t)(accv[mt][nt][3] + bvs);
      *(bf16x4*)&vS[s * ND + (d0 ^ ((s & 7) << 3))] = pv;
    }
  }
  __syncthreads();

  // ---- scores[i][j] = sum_s kT[i][s] qT[j][s]; softmax over i ----
  float ps[16];
  {
    f32x4 sacc[4] = {};
    for (int ks = 0; ks < 4; ++ks) {
      const int kb = ks * 32 + q4 * 8;
      int jrow = w * 16 + l16;
      bf16x8 bfr = *(const bf16x8*)&qT[jrow * NS + swz(jrow, kb)];
      #pragma unroll
      for (int it = 0; it < 4; ++it) {
        int irow = it * 16 + l16;
        bf16x8 afr = *(const bf16x8*)&kT[irow * NS + swz(irow, kb)];
        sacc[it] = MFMA16(afr, bfr, sacc[it], 0, 0, 0);
      }
    }
    const float scale = 0.088388347648318447f;  // 1/sqrt(128)
    float mx = -1e30f;
    #pragma unroll
    for (int it = 0; it < 4; ++it)
      #pragma unroll
      for (int r = 0; r < 4; ++r) {
        float vv = sacc[it][r] * scale;
        ps[it * 4 + r] = vv;
        mx = fmaxf(mx, vv);
      }
    mx = fmaxf(mx, __shfl_xor(mx, 16));
    mx = fmaxf(mx, __shfl_xor(mx, 32));
    float sum = 0.f;
    #pragma unroll
    for (int i = 0; i < 16; ++i) { ps[i] = __expf(ps[i] - mx); sum += ps[i]; }
    sum += __shfl_xor(sum, 16);
    sum += __shfl_xor(sum, 32);
    float inv = 1.f / sum;
    #pragma unroll
    for (int i = 0; i < 16; ++i) ps[i] *= inv;
  }
  __syncthreads();   // all QK^T reads done; aT may overwrite kT region

  {
    int j = w * 16 + l16;
    #pragma unroll
    for (int it = 0; it < 4; ++it) {
      bf16x4 pk;
      #pragma unroll
      for (int r = 0; r < 4; ++r) pk[r] = (bf16_t)ps[it * 4 + r];
      *(bf16x4*)&aT[j * ND + ((it * 16 + q4 * 4) ^ ((j & 7) << 3))] = pk;
    }
  }
  __syncthreads();

  // ---- att[s][j] = sum_i v[s,i] a[i,j] -> attT[j][s] (overlays qT) ----
  {
    const int sbp = w * 32;
    f32x4 pacc[2][4] = {};
    #pragma unroll
    for (int ki = 0; ki < 2; ++ki) {
      const int kb = ki * 32 + q4 * 8;
      bf16x8 afr[2];
      #pragma unroll
      for (int mt = 0; mt < 2; ++mt) {
        int srow = sbp + mt * 16 + l16;
        afr[mt] = *(const bf16x8*)&vS[srow * ND + (kb ^ ((srow & 7) << 3))];
      }
      #pragma unroll
      for (int nt = 0; nt < 4; ++nt) {
        int jrow = nt * 16 + l16;
        bf16x8 bfr = *(const bf16x8*)&aT[jrow * ND + (kb ^ ((jrow & 7) << 3))];
        #pragma unroll
        for (int mt = 0; mt < 2; ++mt)
          pacc[mt][nt] = MFMA16(afr[mt], bfr, pacc[mt][nt], 0, 0, 0);
      }
    }
    #pragma unroll
    for (int nt = 0; nt < 4; ++nt) {
      int j = nt * 16 + l16;
      #pragma unroll
      for (int mt = 0; mt < 2; ++mt) {
        bf16x4 pk;
        #pragma unroll
        for (int r = 0; r < 4; ++r) pk[r] = (bf16_t)pacc[mt][nt][r];
        *(bf16x4*)&attT[j * NS + swz(j, sbp + mt * 16 + q4 * 4)] = pk;
      }
    }
  }
  __syncthreads();

  // ---- dump attT -> att[b][d][hw][s] (linear 16B runs) ----
  #pragma unroll
  for (int jj = 0; jj < 4; ++jj) {
    int f = jj * 2048 + t * 8;
    int d = f >> 7, s0 = f & 127;
    bf16x8 v8 = *(const bf16x8*)&attT[d * NS + (s0 ^ ((d & 7) << 3))];
    *(bf16x8*)(att + ((size_t)((b * ND + d) * NHW + hw)) * NS + s0) = v8;
  }
}

// ================= Kernel C: out projection + residual =================
// grid 1024 = 8(ht of 32hw) * 8(dc of 8d) * 2(ch of 128c) * 8(b)
// Epilogue: acc -> fp32 LDS stage (2 rounds of 64c) -> coalesced float4 I/O.
__global__ __launch_bounds__(256, 2) void out_proj(
    const bf16_t* __restrict__ att_ws,
    const bf16_t* __restrict__ woF, const float* __restrict__ bo,
    const float* __restrict__ x, float* __restrict__ out) {
  __shared__ union {
    bf16_t slab[256 * 128];   // [row=d8*hw32][s128], slot16-XOR by hw&7
    float  stage[64 * 256];   // [c&63][dl*32+hw], hw XOR'd by g<<3
  } sm;
  const int bid = blockIdx.x;
  const int ht = bid & 7, dc = (bid >> 3) & 7, ch = (bid >> 6) & 1, b = bid >> 7;
  const int t = threadIdx.x, w = t >> 6, lane = t & 63;
  const int l16 = lane & 15, g = lane >> 4;
  const int mh = w >> 1, nh = w & 1;

  {
    const int d = t >> 5, hw = t & 31;
    const bf16_t* src = att_ws + ((size_t)((b * ND + dc * 8 + d) * NHW + ht * 32 + hw)) * NS;
    const int row = d * 32 + hw;
    #pragma unroll
    for (int j = 0; j < 16; ++j) {
      bf16x8 v8 = *(const bf16x8*)(src + j * 8);
      *(bf16x8*)&sm.slab[row * NS + ((j ^ (hw & 7)) << 3)] = v8;
    }
  }
  __syncthreads();

  f32x4 acc[4][8] = {};
  #pragma unroll
  for (int kq = 0; kq < 4; ++kq) {
    bf16x8 af[4];
    #pragma unroll
    for (int mt = 0; mt < 4; ++mt) {
      int c = ch * 128 + mh * 64 + mt * 16 + l16;
      af[mt] = *(const bf16x8*)(woF + (kq * 4 + g) * 2048 + c * 8);
    }
    #pragma unroll
    for (int nt = 0; nt < 8; ++nt) {
      int dl = nh * 4 + (nt >> 1);
      int hwl = (nt & 1) * 16 + l16;
      int row = dl * 32 + hwl;
      bf16x8 bfr = *(const bf16x8*)&sm.slab[row * NS + (((kq * 4 + g) ^ (hwl & 7)) << 3)];
      #pragma unroll
      for (int mt = 0; mt < 4; ++mt)
        acc[mt][nt] = MFMA16(af[mt], bfr, acc[mt][nt], 0, 0, 0);
    }
  }

  // ---- staged epilogue: two rounds of 64 c ----
  #pragma unroll
  for (int p = 0; p < 2; ++p) {
    __syncthreads();
    if (mh == p) {
      #pragma unroll
      for (int mt = 0; mt < 4; ++mt) {
        #pragma unroll
        for (int nt = 0; nt < 8; ++nt) {
          int dl = nh * 4 + (nt >> 1);
          int hws = ((nt & 1) * 16 + l16) ^ (g << 3);
          int base = (mt * 16 + g * 4) * 256 + dl * 32 + hws;
          #pragma unroll
          for (int r = 0; r < 4; ++r)
            sm.stage[base + r * 256] = acc[mt][nt][r];
        }
      }
    }
    __syncthreads();
    #pragma unroll
    for (int ii = 0; ii < 16; ++ii) {
      int c6 = ii * 4 + w;                       // wave-uniform
      int c = ch * 128 + p * 64 + c6;
      int dq = (lane >> 3) & 7;
      int hw4 = (lane & 7) * 4;
      float4 v = *(const float4*)&sm.stage[c6 * 256 + dq * 32 + (hw4 ^ ((ii & 3) << 3))];
      size_t gi = ((size_t)(b * NC + c) * ND + dc * 8 + dq) * NHW + ht * 32 + hw4;
      float4 xv = *(const float4*)(x + gi);
      float bias = bo[c];
      float4 o;
      o.x = v.x + bias + xv.x;
      o.y = v.y + bias + xv.y;
      o.z = v.z + bias + xv.z;
      o.w = v.w + bias + xv.w;
      *(float4*)(out + gi) = o;
    }
  }
}

// ================= Fallback: round-1 fused kernel =================
struct SMemF {
  union {
    bf16_t xT[ND * NC];
    struct { bf16_t aT[ND * ND]; bf16_t attT[ND * NS]; } p2;
  } u;
  bf16_t kT[ND * NS];
  bf16_t qT[ND * NS];
  bf16_t vS[NS * ND];
};

__global__ __launch_bounds__(256) void attn_fused(
    const float* __restrict__ x,
    const float* __restrict__ wk, const float* __restrict__ bk,
    const float* __restrict__ wq, const float* __restrict__ bq,
    const float* __restrict__ wv, const float* __restrict__ bv,
    const float* __restrict__ wo, const float* __restrict__ bo,
    float* __restrict__ out) {
  __shared__ SMemF sm;
  const int gid = blockIdx.x;
  const int b = gid & 7;
  const int hw = gid >> 3;
  const int t = threadIdx.x;
  const int w = t >> 6;
  const int lane = t & 63;
  const int l16 = lane & 15;
  const int q4 = lane >> 4;
  const float* xb = x + (size_t)b * NC * ND * NHW + hw;
  {
    const int d = t & 63;
    const int cb = (t >> 6) * 64;
    for (int jj = 0; jj < 8; ++jj) {
      bf16x8 pk;
      #pragma unroll
      for (int e = 0; e < 8; ++e) {
        int c = cb + jj * 8 + e;
        pk[e] = (bf16_t)xb[(size_t)(c * ND + d) * NHW];
      }
      *(bf16x8*)&sm.u.xT[d * NC + swz(d, cb + jj * 8)] = pk;
    }
  }
  __syncthreads();
  {
    const int mat = w >> 1;
    const int sb = (w & 1) * 64;
    const float* wm = mat ? wq : wk;
    const float* bm = mat ? bq : bk;
    bf16_t* dst = mat ? sm.qT : sm.kT;
    f32x4 acc[4][4] = {};
    for (int ks = 0; ks < 8; ++ks) {
      const int kb = ks * 32 + q4 * 8;
      bf16x8 afr[4];
      #pragma unroll
      for (int mt = 0; mt < 4; ++mt) {
        int row = mt * 16 + l16;
        afr[mt] = *(const bf16x8*)&sm.u.xT[row * NC + swz(row, kb)];
      }
      #pragma unroll
      for (int st = 0; st < 4; ++st) {
        int s = sb + st * 16 + l16;
        bf16x8 bfr = ldg_w8(wm + s * NC + kb);
        #pragma unroll
        for (int mt = 0; mt < 4; ++mt)
          acc[mt][st] = MFMA16(afr[mt], bfr, acc[mt][st], 0, 0, 0);
      }
    }
    #pragma unroll
    for (int st = 0; st < 4; ++st) {
      int s = sb + st * 16 + l16;
      float bias = bm[s];
      #pragma unroll
      for (int mt = 0; mt < 4; ++mt) {
        #pragma unroll
        for (int r = 0; r < 4; ++r) {
          int d = mt * 16 + q4 * 4 + r;
          dst[d * NS + swz(d, s)] = (bf16_t)(acc[mt][st][r] + bias);
        }
      }
    }
  }
  {
    const int sb = w * 32;
    f32x4 acc[2][4] = {};
    for (int ks = 0; ks < 8; ++ks) {
      const int kb = ks * 32 + q4 * 8;
      bf16x8 afr[2];
      #pragma unroll
      for (int mt = 0; mt < 2; ++mt)
        afr[mt] = ldg_w8(wv + (sb + mt * 16 + l16) * NC + kb);
      #pragma unroll
      for (int nt = 0; nt < 4; ++nt) {
        int row = nt * 16 + l16;
        bf16x8 bfr = *(const bf16x8*)&sm.u.xT[row * NC + swz(row, kb)];
        #pragma unroll
        for (int mt = 0; mt < 2; ++mt)
          acc[mt][nt] = MFMA16(afr[mt], bfr, acc[mt][nt], 0, 0, 0);
      }
    }
    #pragma unroll
    for (int mt = 0; mt < 2; ++mt) {
      #pragma unroll
      for (int r = 0; r < 4; ++r) {
        int s = sb + mt * 16 + q4 * 4 + r;
        float bias = bv[s];
        #pragma unroll
        for (int nt = 0; nt < 4; ++nt) {
          int d = nt * 16 + l16;
          sm.vS[s * ND + swz(s, d)] = (bf16_t)(acc[mt][nt][r] + bias);
        }
      }
    }
  }
  __syncthreads();
  {
    f32x4 sacc[4] = {};
    for (int ks = 0; ks < 4; ++ks) {
      const int kb = ks * 32 + q4 * 8;
      int jrow = w * 16 + l16;
      bf16x8 bfr = *(const bf16x8*)&sm.qT[jrow * NS + swz(jrow, kb)];
      #pragma unroll
      for (int it = 0; it < 4; ++it) {
        int irow = it * 16 + l16;
        bf16x8 afr = *(const bf16x8*)&sm.kT[irow * NS + swz(irow, kb)];
        sacc[it] = MFMA16(afr, bfr, sacc[it], 0, 0, 0);
      }
    }
    const float scale = 0.088388347648318447f;
    float ps[16];
    float mx = -1e30f;
    #pragma unroll
    for (int it = 0; it < 4; ++it) {
      #pragma unroll
      for (int r = 0; r < 4; ++r) {
        float vv = sacc[it][r] * scale;
        ps[it * 4 + r] = vv;
        mx = fmaxf(mx, vv);
      }
    }
    mx = fmaxf(mx, __shfl_xor(mx, 16));
    mx = fmaxf(mx, __shfl_xor(mx, 32));
    float sum = 0.f;
    #pragma unroll
    for (int i = 0; i < 16; ++i) { ps[i] = __expf(ps[i] - mx); sum += ps[i]; }
    sum += __shfl_xor(sum, 16);
    sum += __shfl_xor(sum, 32);
    float inv = 1.f / sum;
    int j = w * 16 + l16;
    #pragma unroll
    for (int it = 0; it < 4; ++it) {
      bf16x4 pk;
      #pragma unroll
      for (int r = 0; r < 4; ++r) pk[r] = (bf16_t)(ps[it * 4 + r] * inv);
      *(bf16x4*)&sm.u.p2.aT[j * ND + swz(j, it * 16 + q4 * 4)] = pk;
    }
  }
  __syncthreads();
  {
    const int sb = w * 32;
    f32x4 acc[2][4] = {};
    #pragma unroll
    for (int ki = 0; ki < 2; ++ki) {
      const int kb = ki * 32 + q4 * 8;
      bf16x8 afr[2];
      #pragma unroll
      for (int mt = 0; mt < 2; ++mt) {
        int srow = sb + mt * 16 + l16;
        afr[mt] = *(const bf16x8*)&sm.vS[srow * ND + swz(srow, kb)];
      }
      #pragma unroll
      for (int nt = 0; nt < 4; ++nt) {
        int jrow = nt * 16 + l16;
        bf16x8 bfr = *(const bf16x8*)&sm.u.p2.aT[jrow * ND + swz(jrow, kb)];
        #pragma unroll
        for (int mt = 0; mt < 2; ++mt)
          acc[mt][nt] = MFMA16(afr[mt], bfr, acc[mt][nt], 0, 0, 0);
      }
    }
    #pragma unroll
    for (int nt = 0; nt < 4; ++nt) {
      int j = nt * 16 + l16;
      #pragma unroll
      for (int mt = 0; mt < 2; ++mt) {
        bf16x4 pk;
        #pragma unroll
        for (int r = 0; r < 4; ++r) pk[r] = (bf16_t)acc[mt][nt][r];
        *(bf16x4*)&sm.u.p2.attT[j * NS + swz(j, sb + mt * 16 + q4 * 4)] = pk;
      }
    }
  }
  __syncthreads();
  {
    const int cb = w * 64;
    f32x4 acc[4][4] = {};
    for (int ks = 0; ks < 4; ++ks) {
      const int kb = ks * 32 + q4 * 8;
      bf16x8 afr[4];
      #pragma unroll
      for (int mt = 0; mt < 4; ++mt)
        afr[mt] = ldg_w8(wo + (cb + mt * 16 + l16) * NS + kb);
      #pragma unroll
      for (int nt = 0; nt < 4; ++nt) {
        int jrow = nt * 16 + l16;
        bf16x8 bfr = *(const bf16x8*)&sm.u.p2.attT[jrow * NS + swz(jrow, kb)];
        #pragma unroll
        for (int mt = 0; mt < 4; ++mt)
          acc[mt][nt] = MFMA16(afr[mt], bfr, acc[mt][nt], 0, 0, 0);
      }
    }
    #pragma unroll
    for (int mt = 0; mt < 4; ++mt) {
      #pragma unroll
      for (int r = 0; r < 4; ++r) {
        int c = cb + mt * 16 + q4 * 4 + r;
        float bias = bo[c];
        #pragma unroll
        for (int nt = 0; nt < 4; ++nt) {
          int d = nt * 16 + l16;
          size_t gi = (size_t)(((b * NC + c) * ND + d) * NHW + hw);
          out[gi] = acc[mt][nt][r] + bias + x[gi];
        }
      }
    }
  }
}

extern "C" void kernel_launch(void* const* d_in, const int* in_sizes, int n_in,
                              void* d_out, int out_size, void* d_ws, size_t ws_size,
                              hipStream_t stream) {
  const float* x  = (const float*)d_in[0];
  const float* wk = (const float*)d_in[1];
  const float* bk = (const float*)d_in[2];
  const float* wq = (const float*)d_in[3];
  const float* bq = (const float*)d_in[4];
  const float* wv = (const float*)d_in[5];
  const float* bv = (const float*)d_in[6];
  const float* wo = (const float*)d_in[7];
  const float* bo = (const float*)d_in[8];
  float* out = (float*)d_out;

  // ws: [weights bf16 131072 el | xT 33554432 el | att 16777216 el]
  const size_t need = (size_t)(131072 + 33554432 + 16777216) * 2;
  if (ws_size >= need) {
    bf16_t* wsW = (bf16_t*)d_ws;
    bf16_t* xT  = wsW + 131072;
    bf16_t* att = xT + 33554432;
    transpose_x_w<<<dim3(8224), dim3(256), 0, stream>>>(x, wk, wq, wv, wo, xT, wsW);
    qkv_attn3<<<dim3(2048), dim3(256), 0, stream>>>(xT, wsW, bk, bq, bv, att);
    out_proj<<<dim3(1024), dim3(256), 0, stream>>>(att, wsW + 98304, bo, x, out);
  } else {
    attn_fused<<<dim3(2048), dim3(256), 0, stream>>>(x, wk, bk, wq, bq, wv, bv, wo, bo, out);
  }
}